// Round 2
// baseline (2781.668 us; speedup 1.0000x reference)
//
#include <hip/hip_runtime.h>
#include <hip/hip_bf16.h>
#include <math.h>

#define TEMP 0.1
#define NEG_INF_V -1000000000.0

// C[M,N] = A[M,K] @ B[N,K]^T + bias[n]; A,B,bias fp32; fp64 accumulate; OUT_T out.
template <typename OUT_T>
__global__ __launch_bounds__(256) void proj_gemm(
    const float* __restrict__ A, const float* __restrict__ B,
    const float* __restrict__ bias, OUT_T* __restrict__ C,
    int M, int N, int K)
{
    const int BK = 16;
    __shared__ float As[BK][64];
    __shared__ float Bs[BK][64];
    const int tid = threadIdx.x;
    const int tx = tid & 15, ty = tid >> 4;
    const int m0 = blockIdx.y * 64, n0 = blockIdx.x * 64;

    double acc[4][4] = {};

    const int lr = tid >> 2;        // row within tile 0..63
    const int lc = (tid & 3) * 4;   // k offset 0,4,8,12

    const float* aptr = A + (size_t)(m0 + lr) * K + lc;
    const float* bptr = B + (size_t)(n0 + lr) * K + lc;

    for (int k0 = 0; k0 < K; k0 += BK) {
        float4 a4 = *(const float4*)(aptr + k0);
        float4 b4 = *(const float4*)(bptr + k0);
        As[lc + 0][lr] = a4.x; As[lc + 1][lr] = a4.y;
        As[lc + 2][lr] = a4.z; As[lc + 3][lr] = a4.w;
        Bs[lc + 0][lr] = b4.x; Bs[lc + 1][lr] = b4.y;
        Bs[lc + 2][lr] = b4.z; Bs[lc + 3][lr] = b4.w;
        __syncthreads();
#pragma unroll
        for (int kk = 0; kk < BK; ++kk) {
            float4 av = *(const float4*)&As[kk][ty * 4];
            float4 bv = *(const float4*)&Bs[kk][tx * 4];
            double a[4] = {(double)av.x, (double)av.y, (double)av.z, (double)av.w};
            double b[4] = {(double)bv.x, (double)bv.y, (double)bv.z, (double)bv.w};
#pragma unroll
            for (int i = 0; i < 4; ++i)
#pragma unroll
                for (int j = 0; j < 4; ++j)
                    acc[i][j] = fma(a[i], b[j], acc[i][j]);
        }
        __syncthreads();
    }

#pragma unroll
    for (int i = 0; i < 4; ++i) {
        int row = m0 + ty * 4 + i;
#pragma unroll
        for (int j = 0; j < 4; ++j) {
            int col = n0 + tx * 4 + j;
            C[(size_t)row * N + col] = (OUT_T)(acc[i][j] + (double)bias[col]);
        }
    }
}

// C[M,N] = A[M,K] @ B[N,K]^T ; all fp64.
__global__ __launch_bounds__(256) void score_gemm(
    const double* __restrict__ A, const double* __restrict__ B,
    double* __restrict__ C, int M, int N, int K)
{
    const int BK = 16;
    __shared__ __align__(16) double As[BK][64];
    __shared__ __align__(16) double Bs[BK][64];
    const int tid = threadIdx.x;
    const int tx = tid & 15, ty = tid >> 4;
    const int m0 = blockIdx.y * 64, n0 = blockIdx.x * 64;

    double acc[4][4] = {};

    const int lr = tid >> 2;
    const int lc = (tid & 3) * 4;

    const double* aptr = A + (size_t)(m0 + lr) * K + lc;
    const double* bptr = B + (size_t)(n0 + lr) * K + lc;

    for (int k0 = 0; k0 < K; k0 += BK) {
        double2 a01 = *(const double2*)(aptr + k0);
        double2 a23 = *(const double2*)(aptr + k0 + 2);
        double2 b01 = *(const double2*)(bptr + k0);
        double2 b23 = *(const double2*)(bptr + k0 + 2);
        As[lc + 0][lr] = a01.x; As[lc + 1][lr] = a01.y;
        As[lc + 2][lr] = a23.x; As[lc + 3][lr] = a23.y;
        Bs[lc + 0][lr] = b01.x; Bs[lc + 1][lr] = b01.y;
        Bs[lc + 2][lr] = b23.x; Bs[lc + 3][lr] = b23.y;
        __syncthreads();
#pragma unroll
        for (int kk = 0; kk < BK; ++kk) {
            double a[4], b[4];
#pragma unroll
            for (int i = 0; i < 4; ++i) { a[i] = As[kk][ty * 4 + i]; b[i] = Bs[kk][tx * 4 + i]; }
#pragma unroll
            for (int i = 0; i < 4; ++i)
#pragma unroll
                for (int j = 0; j < 4; ++j)
                    acc[i][j] = fma(a[i], b[j], acc[i][j]);
        }
        __syncthreads();
    }

#pragma unroll
    for (int i = 0; i < 4; ++i) {
        int row = m0 + ty * 4 + i;
#pragma unroll
        for (int j = 0; j < 4; ++j)
            C[(size_t)row * N + n0 + tx * 4 + j] = acc[i][j];
    }
}

// In-place fp64 L2 normalization of rows of length 1024.
__global__ __launch_bounds__(256) void l2norm_rows_f64(double* __restrict__ data)
{
    const int row = blockIdx.x;
    const int tid = threadIdx.x;
    double* p = data + (size_t)row * 1024 + tid * 4;
    double v0 = p[0], v1 = p[1], v2 = p[2], v3 = p[3];
    double s = v0 * v0 + v1 * v1 + v2 * v2 + v3 * v3;
#pragma unroll
    for (int off = 32; off > 0; off >>= 1) s += __shfl_down(s, off);
    __shared__ double ws[5];
    if ((tid & 63) == 0) ws[tid >> 6] = s;
    __syncthreads();
    if (tid == 0) {
        double n = sqrt(ws[0] + ws[1] + ws[2] + ws[3]);
        ws[4] = fmax(n, 1e-12);
    }
    __syncthreads();
    double n = ws[4];
    p[0] = v0 / n; p[1] = v1 / n; p[2] = v2 / n; p[3] = v3 / n;
}

// Per q-row: top-8 over 2048 fp64 scores (diag masked), softmax(s/T), weighted V sum.
__global__ __launch_bounds__(256) void topk_route(
    const double* __restrict__ S,   // [2048,2048] this batch
    const float* __restrict__ V,    // [2048,1024] this batch
    float* __restrict__ routes_out,
    float* __restrict__ weights_out,
    float* __restrict__ feat_out,
    int batch)
{
    __shared__ __align__(16) double sc[2048];
    __shared__ double rval[256];
    __shared__ int    ridx[256];
    __shared__ double topv[8];
    __shared__ int    topi[8];
    __shared__ float  w[8];

    const int p = blockIdx.x;
    const int tid = threadIdx.x;
    const double* srow = S + (size_t)p * 2048;

#pragma unroll
    for (int i = 0; i < 4; ++i) {
        int j = tid * 2 + i * 512;
        double2 d = *(const double2*)(srow + j);
        sc[j] = d.x; sc[j + 1] = d.y;
    }
    __syncthreads();
    if (tid == 0) sc[p] = NEG_INF_V;
    __syncthreads();

    for (int it = 0; it < 8; ++it) {
        double bv = -INFINITY; int bi = 0x7fffffff;
#pragma unroll
        for (int r = 0; r < 8; ++r) {
            int j = tid + r * 256;
            double v = sc[j];
            if (v > bv) { bv = v; bi = j; }
        }
        rval[tid] = bv; ridx[tid] = bi;
        __syncthreads();
        for (int off = 128; off > 0; off >>= 1) {
            if (tid < off) {
                double ov = rval[tid + off]; int oi = ridx[tid + off];
                if (ov > rval[tid] || (ov == rval[tid] && oi < ridx[tid])) {
                    rval[tid] = ov; ridx[tid] = oi;
                }
            }
            __syncthreads();
        }
        if (tid == 0) {
            topv[it] = rval[0]; topi[it] = ridx[0];
            sc[ridx[0]] = -INFINITY;
        }
        __syncthreads();
    }

    if (tid == 0) {
        double m = topv[0];
        double e[8], sum = 0.0;
#pragma unroll
        for (int k = 0; k < 8; ++k) { e[k] = exp((topv[k] - m) / TEMP); sum += e[k]; }
#pragma unroll
        for (int k = 0; k < 8; ++k) w[k] = (float)(e[k] / sum);
    }
    __syncthreads();

    const size_t row = (size_t)batch * 2048 + p;
    if (tid < 8) {
        routes_out[row * 8 + tid] = (float)topi[tid];
        weights_out[row * 8 + tid] = w[tid];
    }

    float4 acc = {0.f, 0.f, 0.f, 0.f};
#pragma unroll
    for (int k = 0; k < 8; ++k) {
        const float4 v4 = ((const float4*)(V + (size_t)topi[k] * 1024))[tid];
        float wk = w[k];
        acc.x = fmaf(wk, v4.x, acc.x);
        acc.y = fmaf(wk, v4.y, acc.y);
        acc.z = fmaf(wk, v4.z, acc.z);
        acc.w = fmaf(wk, v4.w, acc.w);
    }
    ((float4*)(feat_out + row * 1024))[tid] = acc;
}

extern "C" void kernel_launch(void* const* d_in, const int* in_sizes, int n_in,
                              void* d_out, int out_size, void* d_ws, size_t ws_size,
                              hipStream_t stream)
{
    const float* x  = (const float*)d_in[0];  // (4,2049,1024)
    const float* Wq = (const float*)d_in[1];
    const float* bq = (const float*)d_in[2];
    const float* Wk = (const float*)d_in[3];
    const float* bk = (const float*)d_in[4];
    const float* Wv = (const float*)d_in[5];
    const float* bv = (const float*)d_in[6];

    const int B = 4, P = 2048, D = 1024;

    double* Qd = (double*)d_ws;               // P*D doubles
    double* Kd = Qd + (size_t)P * D;          // P*D doubles
    double* Sd = Kd + (size_t)P * D;          // P*P doubles
    float*  Vf = (float*)(Sd + (size_t)P * P);// P*D floats

    float* out     = (float*)d_out;
    float* routes  = out;
    float* weights = out + (size_t)B * P * 8;
    float* feat    = out + (size_t)B * P * 16;

    dim3 blk(256);
    for (int b = 0; b < B; ++b) {
        // rows 1..2048 of this batch are contiguous in x
        const float* xb = x + ((size_t)b * 2049 + 1) * D;
        proj_gemm<double><<<dim3(16, 32), blk, 0, stream>>>(xb, Wq, bq, Qd, P, D, D);
        proj_gemm<double><<<dim3(16, 32), blk, 0, stream>>>(xb, Wk, bk, Kd, P, D, D);
        proj_gemm<float ><<<dim3(16, 32), blk, 0, stream>>>(xb, Wv, bv, Vf, P, D, D);
        l2norm_rows_f64<<<dim3(P), blk, 0, stream>>>(Qd);
        l2norm_rows_f64<<<dim3(P), blk, 0, stream>>>(Kd);
        score_gemm<<<dim3(32, 32), blk, 0, stream>>>(Qd, Kd, Sd, P, P, D);
        topk_route<<<dim3(P), blk, 0, stream>>>(Sd, Vf, routes, weights, feat, b);
    }
}

// Round 3
// 2181.693 us; speedup vs baseline: 1.2750x; 1.2750x over previous
//
#include <hip/hip_runtime.h>
#include <hip/hip_bf16.h>
#include <math.h>

#define TEMP 0.1

// ---------- fp64-accumulate projection for Q and K (fused via blockIdx.z) ----------
// C[2048,1024] = x[2048,1024] @ W[1024,1024]^T + b   (fp32 in, fp64 out)
__global__ __launch_bounds__(256) void projqk_f64(
    const float* __restrict__ x,
    const float* __restrict__ Wq, const float* __restrict__ bq,
    const float* __restrict__ Wk, const float* __restrict__ bk,
    double* __restrict__ Qd, double* __restrict__ Kd)
{
    const int K = 1024, N = 1024;
    const float* Bm   = blockIdx.z ? Wk : Wq;
    const float* bias = blockIdx.z ? bk : bq;
    double*      C    = blockIdx.z ? Kd : Qd;

    __shared__ float As[16][64];
    __shared__ float Bs[16][64];
    const int tid = threadIdx.x;
    const int tx = tid & 15, ty = tid >> 4;
    const int m0 = blockIdx.y * 64, n0 = blockIdx.x * 64;

    double acc[4][4] = {};
    const int lr = tid >> 2;
    const int lc = (tid & 3) * 4;
    const float* aptr = x  + (size_t)(m0 + lr) * K + lc;
    const float* bptr = Bm + (size_t)(n0 + lr) * K + lc;

    for (int k0 = 0; k0 < K; k0 += 16) {
        float4 a4 = *(const float4*)(aptr + k0);
        float4 b4 = *(const float4*)(bptr + k0);
        As[lc + 0][lr] = a4.x; As[lc + 1][lr] = a4.y;
        As[lc + 2][lr] = a4.z; As[lc + 3][lr] = a4.w;
        Bs[lc + 0][lr] = b4.x; Bs[lc + 1][lr] = b4.y;
        Bs[lc + 2][lr] = b4.z; Bs[lc + 3][lr] = b4.w;
        __syncthreads();
#pragma unroll
        for (int kk = 0; kk < 16; ++kk) {
            float4 av = *(const float4*)&As[kk][ty * 4];
            float4 bv = *(const float4*)&Bs[kk][tx * 4];
            double a[4] = {(double)av.x, (double)av.y, (double)av.z, (double)av.w};
            double b[4] = {(double)bv.x, (double)bv.y, (double)bv.z, (double)bv.w};
#pragma unroll
            for (int i = 0; i < 4; ++i)
#pragma unroll
                for (int j = 0; j < 4; ++j)
                    acc[i][j] = fma(a[i], b[j], acc[i][j]);
        }
        __syncthreads();
    }

#pragma unroll
    for (int i = 0; i < 4; ++i) {
        int row = m0 + ty * 4 + i;
#pragma unroll
        for (int j = 0; j < 4; ++j) {
            int col = n0 + tx * 4 + j;
            C[(size_t)row * N + col] = acc[i][j] + (double)bias[col];
        }
    }
}

// ---------- fp32 GEMM: C[M,N] = A[M,K] @ B[N,K]^T (+bias) ----------
__global__ __launch_bounds__(256) void gemm_f32(
    const float* __restrict__ A, const float* __restrict__ B,
    const float* __restrict__ bias, float* __restrict__ C,
    int M, int N, int K)
{
    __shared__ float As[16][64];
    __shared__ float Bs[16][64];
    const int tid = threadIdx.x;
    const int tx = tid & 15, ty = tid >> 4;
    const int m0 = blockIdx.y * 64, n0 = blockIdx.x * 64;

    float acc[4][4] = {};
    const int lr = tid >> 2;
    const int lc = (tid & 3) * 4;
    const float* aptr = A + (size_t)(m0 + lr) * K + lc;
    const float* bptr = B + (size_t)(n0 + lr) * K + lc;

    for (int k0 = 0; k0 < K; k0 += 16) {
        float4 a4 = *(const float4*)(aptr + k0);
        float4 b4 = *(const float4*)(bptr + k0);
        As[lc + 0][lr] = a4.x; As[lc + 1][lr] = a4.y;
        As[lc + 2][lr] = a4.z; As[lc + 3][lr] = a4.w;
        Bs[lc + 0][lr] = b4.x; Bs[lc + 1][lr] = b4.y;
        Bs[lc + 2][lr] = b4.z; Bs[lc + 3][lr] = b4.w;
        __syncthreads();
#pragma unroll
        for (int kk = 0; kk < 16; ++kk) {
            float4 av = *(const float4*)&As[kk][ty * 4];
            float4 bv = *(const float4*)&Bs[kk][tx * 4];
            float a[4] = {av.x, av.y, av.z, av.w};
            float b[4] = {bv.x, bv.y, bv.z, bv.w};
#pragma unroll
            for (int i = 0; i < 4; ++i)
#pragma unroll
                for (int j = 0; j < 4; ++j)
                    acc[i][j] = fmaf(a[i], b[j], acc[i][j]);
        }
        __syncthreads();
    }

#pragma unroll
    for (int i = 0; i < 4; ++i) {
        int row = m0 + ty * 4 + i;
#pragma unroll
        for (int j = 0; j < 4; ++j) {
            int col = n0 + tx * 4 + j;
            float v = acc[i][j];
            if (bias) v += bias[col];
            C[(size_t)row * N + col] = v;
        }
    }
}

// ---------- fp64 L2 normalize rows (in place) + fp32 cast copy ----------
__global__ __launch_bounds__(256) void l2norm_cast(
    double* __restrict__ d, float* __restrict__ f)
{
    const int row = blockIdx.x;
    const int tid = threadIdx.x;
    double* p = d + (size_t)row * 1024 + tid * 4;
    double v0 = p[0], v1 = p[1], v2 = p[2], v3 = p[3];
    double s = v0 * v0 + v1 * v1 + v2 * v2 + v3 * v3;
#pragma unroll
    for (int off = 32; off > 0; off >>= 1) s += __shfl_down(s, off);
    __shared__ double ws[5];
    if ((tid & 63) == 0) ws[tid >> 6] = s;
    __syncthreads();
    if (tid == 0) ws[4] = fmax(sqrt(ws[0] + ws[1] + ws[2] + ws[3]), 1e-12);
    __syncthreads();
    double n = ws[4];
    double o0 = v0 / n, o1 = v1 / n, o2 = v2 / n, o3 = v3 / n;
    p[0] = o0; p[1] = o1; p[2] = o2; p[3] = o3;
    float* fp = f + (size_t)row * 1024 + tid * 4;
    fp[0] = (float)o0; fp[1] = (float)o1; fp[2] = (float)o2; fp[3] = (float)o3;
}

// ---------- fp32 top-16 selection + fp64 rerank + softmax + V gather ----------
__global__ __launch_bounds__(256) void topk_route(
    const float*  __restrict__ S,   // [2048,2048] fp32 selection scores
    const double* __restrict__ Qd,  // [2048,1024] fp64 normalized q
    const double* __restrict__ Kd,  // [2048,1024] fp64 normalized k
    const float*  __restrict__ Vf,  // [2048,1024] fp32 v
    float* __restrict__ routes_out,
    float* __restrict__ weights_out,
    float* __restrict__ feat_out,
    int batch)
{
    const int P = 2048, D = 1024;
    __shared__ float  sc[2048];
    __shared__ double qrow[1024];
    __shared__ float  rval[256];
    __shared__ int    ridx[256];
    __shared__ int    cidx[16];
    __shared__ double cscore[16];
    __shared__ int    topi_s[8];
    __shared__ float  wts[8];

    const int p = blockIdx.x;
    const int tid = threadIdx.x;

    // load fp32 score row + fp64 q row
    const float4* sr4 = (const float4*)(S + (size_t)p * P);
    float4* sc4 = (float4*)sc;
    sc4[tid] = sr4[tid];
    sc4[tid + 256] = sr4[tid + 256];
    {
        const double* q = Qd + (size_t)p * D + tid * 4;
        qrow[tid * 4 + 0] = q[0]; qrow[tid * 4 + 1] = q[1];
        qrow[tid * 4 + 2] = q[2]; qrow[tid * 4 + 3] = q[3];
    }
    __syncthreads();
    if (tid == 0) sc[p] = -1e30f;   // mask diagonal
    __syncthreads();

    // 16x block argmax (tie -> smaller index)
    for (int it = 0; it < 16; ++it) {
        float bv = -INFINITY; int bi = 0x7fffffff;
#pragma unroll
        for (int r = 0; r < 8; ++r) {
            int j = tid + r * 256;
            float v = sc[j];
            if (v > bv || (v == bv && j < bi)) { bv = v; bi = j; }
        }
        rval[tid] = bv; ridx[tid] = bi;
        __syncthreads();
        for (int off = 128; off > 0; off >>= 1) {
            if (tid < off) {
                float ov = rval[tid + off]; int oi = ridx[tid + off];
                if (ov > rval[tid] || (ov == rval[tid] && oi < ridx[tid])) {
                    rval[tid] = ov; ridx[tid] = oi;
                }
            }
            __syncthreads();
        }
        if (tid == 0) { cidx[it] = ridx[0]; sc[ridx[0]] = -INFINITY; }
        __syncthreads();
    }

    // fp64 rerank: 16 threads per candidate, 64 elems each
    {
        const int cand = tid >> 4;
        const int l = tid & 15;
        const double* krow = Kd + (size_t)cidx[cand] * D;
        double s = 0.0;
#pragma unroll 8
        for (int j = 0; j < 64; ++j) {
            int e = l + j * 16;
            s = fma(qrow[e], krow[e], s);
        }
        s += __shfl_down(s, 8);
        s += __shfl_down(s, 4);
        s += __shfl_down(s, 2);
        s += __shfl_down(s, 1);
        if (l == 0) cscore[cand] = s;
    }
    __syncthreads();

    if (tid == 0) {
        unsigned used = 0;
        double tv[8]; int ti[8];
        for (int k = 0; k < 8; ++k) {
            int best = -1;
            for (int c = 0; c < 16; ++c) {
                if (used & (1u << c)) continue;
                if (best < 0 || cscore[c] > cscore[best] ||
                    (cscore[c] == cscore[best] && cidx[c] < cidx[best])) best = c;
            }
            used |= 1u << best;
            tv[k] = cscore[best]; ti[k] = cidx[best];
        }
        double m = tv[0], e[8], sum = 0.0;
        for (int k = 0; k < 8; ++k) { e[k] = exp((tv[k] - m) / TEMP); sum += e[k]; }
        const size_t row = (size_t)batch * P + p;
        for (int k = 0; k < 8; ++k) {
            float wk = (float)(e[k] / sum);
            wts[k] = wk; topi_s[k] = ti[k];
            routes_out[row * 8 + k]  = (float)ti[k];
            weights_out[row * 8 + k] = wk;
        }
    }
    __syncthreads();

    float4 acc = {0.f, 0.f, 0.f, 0.f};
#pragma unroll
    for (int k = 0; k < 8; ++k) {
        const float4 v4 = ((const float4*)(Vf + (size_t)topi_s[k] * D))[tid];
        float wk = wts[k];
        acc.x = fmaf(wk, v4.x, acc.x);
        acc.y = fmaf(wk, v4.y, acc.y);
        acc.z = fmaf(wk, v4.z, acc.z);
        acc.w = fmaf(wk, v4.w, acc.w);
    }
    ((float4*)(feat_out + ((size_t)batch * P + p) * D))[tid] = acc;
}

extern "C" void kernel_launch(void* const* d_in, const int* in_sizes, int n_in,
                              void* d_out, int out_size, void* d_ws, size_t ws_size,
                              hipStream_t stream)
{
    const float* x  = (const float*)d_in[0];  // (4,2049,1024)
    const float* Wq = (const float*)d_in[1];
    const float* bq = (const float*)d_in[2];
    const float* Wk = (const float*)d_in[3];
    const float* bk = (const float*)d_in[4];
    const float* Wv = (const float*)d_in[5];
    const float* bv = (const float*)d_in[6];

    const int B = 4, P = 2048, D = 1024;

    double* Qd = (double*)d_ws;                 // P*D f64
    double* Kd = Qd + (size_t)P * D;            // P*D f64
    float*  Qc = (float*)(Kd + (size_t)P * D);  // P*D f32
    float*  Kc = Qc + (size_t)P * D;            // P*D f32
    float*  Vf = Kc + (size_t)P * D;            // P*D f32
    float*  Sf = Vf + (size_t)P * D;            // P*P f32

    float* out     = (float*)d_out;
    float* routes  = out;
    float* weights = out + (size_t)B * P * 8;
    float* feat    = out + (size_t)B * P * 16;

    dim3 blk(256);
    for (int b = 0; b < B; ++b) {
        const float* xb = x + ((size_t)b * 2049 + 1) * D;  // rows 1..2048 contiguous
        projqk_f64<<<dim3(16, 32, 2), blk, 0, stream>>>(xb, Wq, bq, Wk, bk, Qd, Kd);
        gemm_f32<<<dim3(16, 32), blk, 0, stream>>>(xb, Wv, bv, Vf, P, D, D);
        l2norm_cast<<<dim3(P), blk, 0, stream>>>(Qd, Qc);
        l2norm_cast<<<dim3(P), blk, 0, stream>>>(Kd, Kc);
        gemm_f32<<<dim3(32, 32), blk, 0, stream>>>(Qc, Kc, nullptr, Sf, P, P, D);
        topk_route<<<dim3(P), blk, 0, stream>>>(Sf, Qd, Kd, Vf, routes, weights, feat, b);
    }
}

// Round 5
// 1803.790 us; speedup vs baseline: 1.5421x; 1.2095x over previous
//
#include <hip/hip_runtime.h>
#include <hip/hip_bf16.h>
#include <math.h>

#define TEMP 0.1

typedef float f4 __attribute__((ext_vector_type(4)));
typedef short s8v __attribute__((ext_vector_type(8)));

__device__ inline short f2bf(float f) {
    __hip_bfloat16 h = __float2bfloat16(f);
    return *reinterpret_cast<short*>(&h);
}
__device__ inline float bf2f(short s) {
    __hip_bfloat16 h = *reinterpret_cast<__hip_bfloat16*>(&s);
    return __bfloat162float(h);
}

// ---------- fp64-accumulate (vector) projection for Q and K — R2-proven ----------
__global__ __launch_bounds__(256) void projqk_f64(
    const float* __restrict__ x,
    const float* __restrict__ Wq, const float* __restrict__ bq,
    const float* __restrict__ Wk, const float* __restrict__ bk,
    double* __restrict__ Qd, double* __restrict__ Kd)
{
    const int K = 1024, N = 1024;
    const float* Bm   = blockIdx.z ? Wk : Wq;
    const float* bias = blockIdx.z ? bk : bq;
    double*      C    = blockIdx.z ? Kd : Qd;

    __shared__ float As[16][64];
    __shared__ float Bs[16][64];
    const int tid = threadIdx.x;
    const int tx = tid & 15, ty = tid >> 4;
    const int m0 = blockIdx.y * 64, n0 = blockIdx.x * 64;

    double acc[4][4] = {};
    const int lr = tid >> 2;
    const int lc = (tid & 3) * 4;
    const float* aptr = x  + (size_t)(m0 + lr) * K + lc;
    const float* bptr = Bm + (size_t)(n0 + lr) * K + lc;

    for (int k0 = 0; k0 < K; k0 += 16) {
        float4 a4 = *(const float4*)(aptr + k0);
        float4 b4 = *(const float4*)(bptr + k0);
        As[lc + 0][lr] = a4.x; As[lc + 1][lr] = a4.y;
        As[lc + 2][lr] = a4.z; As[lc + 3][lr] = a4.w;
        Bs[lc + 0][lr] = b4.x; Bs[lc + 1][lr] = b4.y;
        Bs[lc + 2][lr] = b4.z; Bs[lc + 3][lr] = b4.w;
        __syncthreads();
#pragma unroll
        for (int kk = 0; kk < 16; ++kk) {
            float4 av = *(const float4*)&As[kk][ty * 4];
            float4 bv = *(const float4*)&Bs[kk][tx * 4];
            double a[4] = {(double)av.x, (double)av.y, (double)av.z, (double)av.w};
            double b[4] = {(double)bv.x, (double)bv.y, (double)bv.z, (double)bv.w};
#pragma unroll
            for (int i = 0; i < 4; ++i)
#pragma unroll
                for (int j = 0; j < 4; ++j)
                    acc[i][j] = fma(a[i], b[j], acc[i][j]);
        }
        __syncthreads();
    }

#pragma unroll
    for (int i = 0; i < 4; ++i) {
        int row = m0 + ty * 4 + i;
#pragma unroll
        for (int j = 0; j < 4; ++j) {
            int col = n0 + tx * 4 + j;
            C[(size_t)row * N + col] = acc[i][j] + (double)bias[col];
        }
    }
}

// ---------------- bf16 MFMA GEMM: C = A @ B^T (+bias), fp32 in/out --------------
// SPLIT=0: plain bf16 (selection-grade). SPLIT=1: hi/lo split, ~fp32 accuracy.
template <int SPLIT>
__global__ __launch_bounds__(256) void gemm_bf16(
    const float* __restrict__ A, const float* __restrict__ B,
    const float* __restrict__ bias, float* __restrict__ C,
    int M, int N, int K)
{
    __shared__ short Ah[128][40];
    __shared__ short Bh[128][40];
    __shared__ short Al[SPLIT ? 128 : 1][40];
    __shared__ short Bl[SPLIT ? 128 : 1][40];

    const int tid  = threadIdx.x;
    const int lane = tid & 63, wave = tid >> 6;
    const int wm = wave >> 1, wn = wave & 1;      // 2x2 waves, 64x64 each
    const int quad = lane >> 4, l16 = lane & 15;
    const int m0 = blockIdx.y * 128, n0 = blockIdx.x * 128;

    const int srow = tid >> 1, sco = (tid & 1) * 16;
    const float* ap = A + (size_t)(m0 + srow) * K + sco;
    const float* bp = B + (size_t)(n0 + srow) * K + sco;

    f4 acc[4][4] = {};

    for (int k0 = 0; k0 < K; k0 += 32) {
        float av[16], bv[16];
#pragma unroll
        for (int i = 0; i < 4; ++i) {
            *(float4*)&av[i * 4] = *(const float4*)(ap + k0 + i * 4);
            *(float4*)&bv[i * 4] = *(const float4*)(bp + k0 + i * 4);
        }
        __align__(16) short ahv[16], bhv[16], alv[16], blv[16];
#pragma unroll
        for (int i = 0; i < 16; ++i) {
            short h = f2bf(av[i]); ahv[i] = h;
            if (SPLIT) alv[i] = f2bf(av[i] - bf2f(h));
            short g = f2bf(bv[i]); bhv[i] = g;
            if (SPLIT) blv[i] = f2bf(bv[i] - bf2f(g));
        }
        __syncthreads();
        *(s8v*)&Ah[srow][sco]     = *(s8v*)&ahv[0];
        *(s8v*)&Ah[srow][sco + 8] = *(s8v*)&ahv[8];
        *(s8v*)&Bh[srow][sco]     = *(s8v*)&bhv[0];
        *(s8v*)&Bh[srow][sco + 8] = *(s8v*)&bhv[8];
        if (SPLIT) {
            *(s8v*)&Al[srow][sco]     = *(s8v*)&alv[0];
            *(s8v*)&Al[srow][sco + 8] = *(s8v*)&alv[8];
            *(s8v*)&Bl[srow][sco]     = *(s8v*)&blv[0];
            *(s8v*)&Bl[srow][sco + 8] = *(s8v*)&blv[8];
        }
        __syncthreads();

        s8v af[4], bfr[4], afl[4], bfl[4];
#pragma unroll
        for (int t = 0; t < 4; ++t) {
            af[t]  = *(s8v*)&Ah[wm * 64 + t * 16 + l16][quad * 8];
            bfr[t] = *(s8v*)&Bh[wn * 64 + t * 16 + l16][quad * 8];
            if (SPLIT) {
                afl[t] = *(s8v*)&Al[wm * 64 + t * 16 + l16][quad * 8];
                bfl[t] = *(s8v*)&Bl[wn * 64 + t * 16 + l16][quad * 8];
            }
        }
#pragma unroll
        for (int mt = 0; mt < 4; ++mt)
#pragma unroll
            for (int nt = 0; nt < 4; ++nt) {
                acc[mt][nt] = __builtin_amdgcn_mfma_f32_16x16x32_bf16(
                    af[mt], bfr[nt], acc[mt][nt], 0, 0, 0);
                if (SPLIT) {
                    acc[mt][nt] = __builtin_amdgcn_mfma_f32_16x16x32_bf16(
                        af[mt], bfl[nt], acc[mt][nt], 0, 0, 0);
                    acc[mt][nt] = __builtin_amdgcn_mfma_f32_16x16x32_bf16(
                        afl[mt], bfr[nt], acc[mt][nt], 0, 0, 0);
                }
            }
    }

#pragma unroll
    for (int mt = 0; mt < 4; ++mt)
#pragma unroll
        for (int nt = 0; nt < 4; ++nt)
#pragma unroll
            for (int r = 0; r < 4; ++r) {
                int row = m0 + wm * 64 + mt * 16 + quad * 4 + r;
                int col = n0 + wn * 64 + nt * 16 + l16;
                float v = acc[mt][nt][r];
                if (bias) v += bias[col];
                C[(size_t)row * N + col] = v;
            }
}

// ---------------- fp64 L2 normalize rows (in place) + fp32 copy ----------------
__global__ __launch_bounds__(256) void l2norm_f64f32(
    double* __restrict__ d, float* __restrict__ f)
{
    const int row = blockIdx.x;
    const int tid = threadIdx.x;
    double* p = d + (size_t)row * 1024 + tid * 4;
    double v0 = p[0], v1 = p[1], v2 = p[2], v3 = p[3];
    double s = v0 * v0 + v1 * v1 + v2 * v2 + v3 * v3;
#pragma unroll
    for (int off = 32; off > 0; off >>= 1) s += __shfl_down(s, off);
    __shared__ double ws[5];
    if ((tid & 63) == 0) ws[tid >> 6] = s;
    __syncthreads();
    if (tid == 0) ws[4] = fmax(sqrt(ws[0] + ws[1] + ws[2] + ws[3]), 1e-12);
    __syncthreads();
    double n = ws[4];
    double o0 = v0 / n, o1 = v1 / n, o2 = v2 / n, o3 = v3 / n;
    p[0] = o0; p[1] = o1; p[2] = o2; p[3] = o3;
    float* fp = f + (size_t)row * 1024 + tid * 4;
    fp[0] = (float)o0; fp[1] = (float)o1; fp[2] = (float)o2; fp[3] = (float)o3;
}

// ------- fp32 top-16 selection + fp64 rerank + softmax + V gather — R2-proven -------
__global__ __launch_bounds__(256) void topk_route(
    const float*  __restrict__ S,
    const double* __restrict__ Qd,
    const double* __restrict__ Kd,
    const float*  __restrict__ Vf,
    float* __restrict__ routes_out,
    float* __restrict__ weights_out,
    float* __restrict__ feat_out,
    int batch)
{
    const int P = 2048, D = 1024;
    __shared__ float  sc[2048];
    __shared__ double qrow[1024];
    __shared__ float  rval[256];
    __shared__ int    ridx[256];
    __shared__ int    cidx[16];
    __shared__ double cscore[16];
    __shared__ int    topi_s[8];
    __shared__ float  wts[8];

    const int p = blockIdx.x;
    const int tid = threadIdx.x;

    const float4* sr4 = (const float4*)(S + (size_t)p * P);
    float4* sc4 = (float4*)sc;
    sc4[tid] = sr4[tid];
    sc4[tid + 256] = sr4[tid + 256];
    {
        const double* q = Qd + (size_t)p * D + tid * 4;
        qrow[tid * 4 + 0] = q[0]; qrow[tid * 4 + 1] = q[1];
        qrow[tid * 4 + 2] = q[2]; qrow[tid * 4 + 3] = q[3];
    }
    __syncthreads();
    if (tid == 0) sc[p] = -1e30f;
    __syncthreads();

    for (int it = 0; it < 16; ++it) {
        float bv = -INFINITY; int bi = 0x7fffffff;
#pragma unroll
        for (int r = 0; r < 8; ++r) {
            int j = tid + r * 256;
            float v = sc[j];
            if (v > bv || (v == bv && j < bi)) { bv = v; bi = j; }
        }
        rval[tid] = bv; ridx[tid] = bi;
        __syncthreads();
        for (int off = 128; off > 0; off >>= 1) {
            if (tid < off) {
                float ov = rval[tid + off]; int oi = ridx[tid + off];
                if (ov > rval[tid] || (ov == rval[tid] && oi < ridx[tid])) {
                    rval[tid] = ov; ridx[tid] = oi;
                }
            }
            __syncthreads();
        }
        if (tid == 0) { cidx[it] = ridx[0]; sc[ridx[0]] = -INFINITY; }
        __syncthreads();
    }

    {
        const int cand = tid >> 4;
        const int l = tid & 15;
        const double* krow = Kd + (size_t)cidx[cand] * D;
        double s = 0.0;
#pragma unroll 8
        for (int j = 0; j < 64; ++j) {
            int e = l + j * 16;
            s = fma(qrow[e], krow[e], s);
        }
        s += __shfl_down(s, 8);
        s += __shfl_down(s, 4);
        s += __shfl_down(s, 2);
        s += __shfl_down(s, 1);
        if (l == 0) cscore[cand] = s;
    }
    __syncthreads();

    if (tid == 0) {
        unsigned used = 0;
        double tv[8]; int ti[8];
        for (int k = 0; k < 8; ++k) {
            int best = -1;
            for (int c = 0; c < 16; ++c) {
                if (used & (1u << c)) continue;
                if (best < 0 || cscore[c] > cscore[best] ||
                    (cscore[c] == cscore[best] && cidx[c] < cidx[best])) best = c;
            }
            used |= 1u << best;
            tv[k] = cscore[best]; ti[k] = cidx[best];
        }
        double m = tv[0], e[8], sum = 0.0;
        for (int k = 0; k < 8; ++k) { e[k] = exp((tv[k] - m) / TEMP); sum += e[k]; }
        const size_t row = (size_t)batch * P + p;
        for (int k = 0; k < 8; ++k) {
            float wk = (float)(e[k] / sum);
            wts[k] = wk; topi_s[k] = ti[k];
            routes_out[row * 8 + k]  = (float)ti[k];
            weights_out[row * 8 + k] = wk;
        }
    }
    __syncthreads();

    float4 a = {0.f, 0.f, 0.f, 0.f};
#pragma unroll
    for (int k = 0; k < 8; ++k) {
        const float4 v4 = ((const float4*)(Vf + (size_t)topi_s[k] * D))[tid];
        float wk = wts[k];
        a.x = fmaf(wk, v4.x, a.x);
        a.y = fmaf(wk, v4.y, a.y);
        a.z = fmaf(wk, v4.z, a.z);
        a.w = fmaf(wk, v4.w, a.w);
    }
    ((float4*)(feat_out + ((size_t)batch * P + p) * D))[tid] = a;
}

extern "C" void kernel_launch(void* const* d_in, const int* in_sizes, int n_in,
                              void* d_out, int out_size, void* d_ws, size_t ws_size,
                              hipStream_t stream)
{
    const float* x  = (const float*)d_in[0];  // (4,2049,1024)
    const float* Wq = (const float*)d_in[1];
    const float* bq = (const float*)d_in[2];
    const float* Wk = (const float*)d_in[3];
    const float* bk = (const float*)d_in[4];
    const float* Wv = (const float*)d_in[5];
    const float* bv = (const float*)d_in[6];

    const int B = 4, P = 2048, D = 1024;

    double* Qd = (double*)d_ws;                 // P*D f64
    double* Kd = Qd + (size_t)P * D;            // P*D f64
    float*  Qf = (float*)(Kd + (size_t)P * D);  // P*D f32 (normalized)
    float*  Kf = Qf + (size_t)P * D;
    float*  Vf = Kf + (size_t)P * D;
    float*  Sf = Vf + (size_t)P * D;            // P*P f32

    float* out     = (float*)d_out;
    float* routes  = out;
    float* weights = out + (size_t)B * P * 8;
    float* feat    = out + (size_t)B * P * 16;

    dim3 blk(256);
    for (int b = 0; b < B; ++b) {
        const float* xb = x + ((size_t)b * 2049 + 1) * D;  // rows 1..2048 contiguous
        projqk_f64<<<dim3(16, 32, 2), blk, 0, stream>>>(xb, Wq, bq, Wk, bk, Qd, Kd);
        gemm_bf16<1><<<dim3(8, 16), blk, 0, stream>>>(xb, Wv, bv, Vf, P, D, D);
        l2norm_f64f32<<<dim3(P), blk, 0, stream>>>(Qd, Qf);
        l2norm_f64f32<<<dim3(P), blk, 0, stream>>>(Kd, Kf);
        gemm_bf16<0><<<dim3(16, 16), blk, 0, stream>>>(Qf, Kf, nullptr, Sf, P, P, D);
        topk_route<<<dim3(P), blk, 0, stream>>>(Sf, Qd, Kd, Vf, routes, weights, feat, b);
    }
}

// Round 6
// 1397.966 us; speedup vs baseline: 1.9898x; 1.2903x over previous
//
#include <hip/hip_runtime.h>
#include <hip/hip_bf16.h>
#include <math.h>

#define TEMP 0.1

typedef float f4 __attribute__((ext_vector_type(4)));
typedef short s8v __attribute__((ext_vector_type(8)));
typedef int   i4v __attribute__((ext_vector_type(4)));

__device__ inline short f2bf(float f) {
    __hip_bfloat16 h = __float2bfloat16(f);
    return *reinterpret_cast<short*>(&h);
}
__device__ inline float bf2f(short s) {
    __hip_bfloat16 h = *reinterpret_cast<__hip_bfloat16*>(&s);
    return __bfloat162float(h);
}

// ---------- quantize rows of length 1024 to 5 balanced int8 limbs ----------
// X = round(x * 2^sigma), sigma = 37 - ilogb(rowmax)  =>  |X| < 2^38, top limb |d4|<=64.
// x = (sum_l limb_l * 256^l) * 2^-sigma  exactly up to the rounding quantum.
__global__ __launch_bounds__(256) void quantize_rows(
    const float* __restrict__ src, signed char* __restrict__ limbs,
    long plane_stride, double* __restrict__ scale)
{
    const int row = blockIdx.x, tid = threadIdx.x;
    const float4 v = ((const float4*)(src + (size_t)row * 1024))[tid];
    float m = fmaxf(fmaxf(fabsf(v.x), fabsf(v.y)), fmaxf(fabsf(v.z), fabsf(v.w)));
#pragma unroll
    for (int off = 32; off > 0; off >>= 1) m = fmaxf(m, __shfl_down(m, off));
    __shared__ float wmax[4];
    __shared__ int ssig;
    if ((tid & 63) == 0) wmax[tid >> 6] = m;
    __syncthreads();
    if (tid == 0) {
        float rm = fmaxf(fmaxf(wmax[0], wmax[1]), fmaxf(wmax[2], wmax[3]));
        int sig = (rm > 0.f) ? (37 - ilogbf(rm)) : 0;
        ssig = sig;
        scale[row] = ldexp(1.0, -sig);
    }
    __syncthreads();
    const double s2 = ldexp(1.0, ssig);
    float xs[4] = {v.x, v.y, v.z, v.w};
    signed char out[5][4];
#pragma unroll
    for (int e = 0; e < 4; ++e) {
        long X = __double2ll_rn((double)xs[e] * s2);
#pragma unroll
        for (int l = 0; l < 4; ++l) {
            int d = (int)(((X + 128) & 255) - 128);
            out[l][e] = (signed char)d;
            X = (X - d) >> 8;
        }
        out[4][e] = (signed char)X;
    }
#pragma unroll
    for (int l = 0; l < 5; ++l)
        *(char4*)&limbs[(size_t)l * plane_stride + (size_t)row * 1024 + tid * 4] =
            *(char4*)&out[l][0];
}

// ---------- exact-precision projection via i8 MFMA on limb planes ----------
// C_f64[2048,1024] = x @ W^T + b, reconstructed from 19 limb-pair passes (i+j>=3),
// 6 i32 accumulator levels (s=i+j-3), exact i32 accumulation, fp64 recombine.
__global__ __launch_bounds__(256) void gemm_i8qk(
    const signed char* __restrict__ Xl,   // [5][2048][1024]
    const signed char* __restrict__ Wql,  // [5][1024][1024]
    const signed char* __restrict__ Wkl,
    const double* __restrict__ xsc,       // [2048] 2^-sigma_m
    const double* __restrict__ wqsc, const double* __restrict__ wksc, // [1024]
    const float* __restrict__ bq, const float* __restrict__ bk,
    double* __restrict__ Qd, double* __restrict__ Kd)
{
    const int K = 1024, N = 1024;
    const long MK = 2048L * 1024, NK = 1024L * 1024;
    const signed char* Wl = blockIdx.z ? Wkl : Wql;
    const double* wsc = blockIdx.z ? wksc : wqsc;
    const float* bias = blockIdx.z ? bk : bq;
    double* C = blockIdx.z ? Kd : Qd;

    // stride 80 bytes per row: 16B accesses land 2-way on banks (free)
    __shared__ __align__(16) signed char Asm[5][64][80];
    __shared__ __align__(16) signed char Bsm[5][64][80];

    const int tid  = threadIdx.x;
    const int lane = tid & 63, wave = tid >> 6;
    const int wm = wave >> 1, wn = wave & 1;     // 2x2 waves, 32x32 out each
    const int quad = lane >> 4, l16 = lane & 15;
    const int m0 = blockIdx.y * 64, n0 = blockIdx.x * 64;

    const int srow = tid >> 2, skq = (tid & 3) * 16;
    const signed char* ap = Xl + (size_t)(m0 + srow) * K + skq;
    const signed char* bp = Wl + (size_t)(n0 + srow) * K + skq;

    i4v acc[6][2][2] = {};   // [level s-3][mtile][ntile]

    for (int k0 = 0; k0 < K; k0 += 64) {
        i4v at[5], bt[5];
#pragma unroll
        for (int l = 0; l < 5; ++l) {
            at[l] = *(const i4v*)(ap + l * MK + k0);
            bt[l] = *(const i4v*)(bp + l * NK + k0);
        }
        __syncthreads();
#pragma unroll
        for (int l = 0; l < 5; ++l) {
            *(i4v*)&Asm[l][srow][skq] = at[l];
            *(i4v*)&Bsm[l][srow][skq] = bt[l];
        }
        __syncthreads();

        i4v bF[5][2];
#pragma unroll
        for (int j = 0; j < 5; ++j)
#pragma unroll
            for (int nt = 0; nt < 2; ++nt)
                bF[j][nt] = *(const i4v*)&Bsm[j][wn * 32 + nt * 16 + l16][quad * 16];

#pragma unroll
        for (int i = 0; i < 5; ++i) {
            i4v a0 = *(const i4v*)&Asm[i][wm * 32 +      l16][quad * 16];
            i4v a1 = *(const i4v*)&Asm[i][wm * 32 + 16 + l16][quad * 16];
#pragma unroll
            for (int j = 0; j < 5; ++j) {
                if (i + j < 3) continue;
                const int s = i + j - 3;
                acc[s][0][0] = __builtin_amdgcn_mfma_i32_16x16x64_i8(a0, bF[j][0], acc[s][0][0], 0, 0, 0);
                acc[s][0][1] = __builtin_amdgcn_mfma_i32_16x16x64_i8(a0, bF[j][1], acc[s][0][1], 0, 0, 0);
                acc[s][1][0] = __builtin_amdgcn_mfma_i32_16x16x64_i8(a1, bF[j][0], acc[s][1][0], 0, 0, 0);
                acc[s][1][1] = __builtin_amdgcn_mfma_i32_16x16x64_i8(a1, bF[j][1], acc[s][1][1], 0, 0, 0);
            }
        }
    }

    const double wt0 = ldexp(1.0, 24), wt1 = ldexp(1.0, 32), wt2 = ldexp(1.0, 40);
    const double wt3 = ldexp(1.0, 48), wt4 = ldexp(1.0, 56), wt5 = ldexp(1.0, 64);
#pragma unroll
    for (int mt = 0; mt < 2; ++mt)
#pragma unroll
        for (int nt = 0; nt < 2; ++nt)
#pragma unroll
            for (int r = 0; r < 4; ++r) {
                int row = m0 + wm * 32 + mt * 16 + quad * 4 + r;
                int col = n0 + wn * 32 + nt * 16 + l16;
                double dsum = wt0 * (double)acc[0][mt][nt][r]
                            + wt1 * (double)acc[1][mt][nt][r]
                            + wt2 * (double)acc[2][mt][nt][r]
                            + wt3 * (double)acc[3][mt][nt][r]
                            + wt4 * (double)acc[4][mt][nt][r]
                            + wt5 * (double)acc[5][mt][nt][r];
                C[(size_t)row * N + col] = dsum * xsc[row] * wsc[col] + (double)bias[col];
            }
}

// ---------------- bf16 MFMA GEMM: C = A @ B^T (+bias), fp32 in/out — R4-proven ----
template <int SPLIT>
__global__ __launch_bounds__(256) void gemm_bf16(
    const float* __restrict__ A, const float* __restrict__ B,
    const float* __restrict__ bias, float* __restrict__ C,
    int M, int N, int K)
{
    __shared__ short Ah[128][40];
    __shared__ short Bh[128][40];
    __shared__ short Al[SPLIT ? 128 : 1][40];
    __shared__ short Bl[SPLIT ? 128 : 1][40];

    const int tid  = threadIdx.x;
    const int lane = tid & 63, wave = tid >> 6;
    const int wm = wave >> 1, wn = wave & 1;
    const int quad = lane >> 4, l16 = lane & 15;
    const int m0 = blockIdx.y * 128, n0 = blockIdx.x * 128;

    const int srow = tid >> 1, sco = (tid & 1) * 16;
    const float* ap = A + (size_t)(m0 + srow) * K + sco;
    const float* bp = B + (size_t)(n0 + srow) * K + sco;

    f4 acc[4][4] = {};

    for (int k0 = 0; k0 < K; k0 += 32) {
        float av[16], bv[16];
#pragma unroll
        for (int i = 0; i < 4; ++i) {
            *(float4*)&av[i * 4] = *(const float4*)(ap + k0 + i * 4);
            *(float4*)&bv[i * 4] = *(const float4*)(bp + k0 + i * 4);
        }
        __align__(16) short ahv[16], bhv[16], alv[16], blv[16];
#pragma unroll
        for (int i = 0; i < 16; ++i) {
            short h = f2bf(av[i]); ahv[i] = h;
            if (SPLIT) alv[i] = f2bf(av[i] - bf2f(h));
            short g = f2bf(bv[i]); bhv[i] = g;
            if (SPLIT) blv[i] = f2bf(bv[i] - bf2f(g));
        }
        __syncthreads();
        *(s8v*)&Ah[srow][sco]     = *(s8v*)&ahv[0];
        *(s8v*)&Ah[srow][sco + 8] = *(s8v*)&ahv[8];
        *(s8v*)&Bh[srow][sco]     = *(s8v*)&bhv[0];
        *(s8v*)&Bh[srow][sco + 8] = *(s8v*)&bhv[8];
        if (SPLIT) {
            *(s8v*)&Al[srow][sco]     = *(s8v*)&alv[0];
            *(s8v*)&Al[srow][sco + 8] = *(s8v*)&alv[8];
            *(s8v*)&Bl[srow][sco]     = *(s8v*)&blv[0];
            *(s8v*)&Bl[srow][sco + 8] = *(s8v*)&blv[8];
        }
        __syncthreads();

        s8v af[4], bfr[4], afl[4], bfl[4];
#pragma unroll
        for (int t = 0; t < 4; ++t) {
            af[t]  = *(s8v*)&Ah[wm * 64 + t * 16 + l16][quad * 8];
            bfr[t] = *(s8v*)&Bh[wn * 64 + t * 16 + l16][quad * 8];
            if (SPLIT) {
                afl[t] = *(s8v*)&Al[wm * 64 + t * 16 + l16][quad * 8];
                bfl[t] = *(s8v*)&Bl[wn * 64 + t * 16 + l16][quad * 8];
            }
        }
#pragma unroll
        for (int mt = 0; mt < 4; ++mt)
#pragma unroll
            for (int nt = 0; nt < 4; ++nt) {
                acc[mt][nt] = __builtin_amdgcn_mfma_f32_16x16x32_bf16(
                    af[mt], bfr[nt], acc[mt][nt], 0, 0, 0);
                if (SPLIT) {
                    acc[mt][nt] = __builtin_amdgcn_mfma_f32_16x16x32_bf16(
                        af[mt], bfl[nt], acc[mt][nt], 0, 0, 0);
                    acc[mt][nt] = __builtin_amdgcn_mfma_f32_16x16x32_bf16(
                        afl[mt], bfr[nt], acc[mt][nt], 0, 0, 0);
                }
            }
    }

#pragma unroll
    for (int mt = 0; mt < 4; ++mt)
#pragma unroll
        for (int nt = 0; nt < 4; ++nt)
#pragma unroll
            for (int r = 0; r < 4; ++r) {
                int row = m0 + wm * 64 + mt * 16 + quad * 4 + r;
                int col = n0 + wn * 64 + nt * 16 + l16;
                float v = acc[mt][nt][r];
                if (bias) v += bias[col];
                C[(size_t)row * N + col] = v;
            }
}

// ---------------- fp64 L2 normalize rows (in place) + fp32 copy ----------------
__global__ __launch_bounds__(256) void l2norm_f64f32(
    double* __restrict__ d, float* __restrict__ f)
{
    const int row = blockIdx.x;
    const int tid = threadIdx.x;
    double* p = d + (size_t)row * 1024 + tid * 4;
    double v0 = p[0], v1 = p[1], v2 = p[2], v3 = p[3];
    double s = v0 * v0 + v1 * v1 + v2 * v2 + v3 * v3;
#pragma unroll
    for (int off = 32; off > 0; off >>= 1) s += __shfl_down(s, off);
    __shared__ double ws[5];
    if ((tid & 63) == 0) ws[tid >> 6] = s;
    __syncthreads();
    if (tid == 0) ws[4] = fmax(sqrt(ws[0] + ws[1] + ws[2] + ws[3]), 1e-12);
    __syncthreads();
    double n = ws[4];
    double o0 = v0 / n, o1 = v1 / n, o2 = v2 / n, o3 = v3 / n;
    p[0] = o0; p[1] = o1; p[2] = o2; p[3] = o3;
    float* fp = f + (size_t)row * 1024 + tid * 4;
    fp[0] = (float)o0; fp[1] = (float)o1; fp[2] = (float)o2; fp[3] = (float)o3;
}

// ------- fp32 top-16 selection + fp64 rerank + softmax + V gather — R2-proven -------
__global__ __launch_bounds__(256) void topk_route(
    const float*  __restrict__ S,
    const double* __restrict__ Qd,
    const double* __restrict__ Kd,
    const float*  __restrict__ Vf,
    float* __restrict__ routes_out,
    float* __restrict__ weights_out,
    float* __restrict__ feat_out,
    int batch)
{
    const int P = 2048, D = 1024;
    __shared__ float  sc[2048];
    __shared__ double qrow[1024];
    __shared__ float  rval[256];
    __shared__ int    ridx[256];
    __shared__ int    cidx[16];
    __shared__ double cscore[16];
    __shared__ int    topi_s[8];
    __shared__ float  wts[8];

    const int p = blockIdx.x;
    const int tid = threadIdx.x;

    const float4* sr4 = (const float4*)(S + (size_t)p * P);
    float4* sc4 = (float4*)sc;
    sc4[tid] = sr4[tid];
    sc4[tid + 256] = sr4[tid + 256];
    {
        const double* q = Qd + (size_t)p * D + tid * 4;
        qrow[tid * 4 + 0] = q[0]; qrow[tid * 4 + 1] = q[1];
        qrow[tid * 4 + 2] = q[2]; qrow[tid * 4 + 3] = q[3];
    }
    __syncthreads();
    if (tid == 0) sc[p] = -1e30f;
    __syncthreads();

    for (int it = 0; it < 16; ++it) {
        float bv = -INFINITY; int bi = 0x7fffffff;
#pragma unroll
        for (int r = 0; r < 8; ++r) {
            int j = tid + r * 256;
            float v = sc[j];
            if (v > bv || (v == bv && j < bi)) { bv = v; bi = j; }
        }
        rval[tid] = bv; ridx[tid] = bi;
        __syncthreads();
        for (int off = 128; off > 0; off >>= 1) {
            if (tid < off) {
                float ov = rval[tid + off]; int oi = ridx[tid + off];
                if (ov > rval[tid] || (ov == rval[tid] && oi < ridx[tid])) {
                    rval[tid] = ov; ridx[tid] = oi;
                }
            }
            __syncthreads();
        }
        if (tid == 0) { cidx[it] = ridx[0]; sc[ridx[0]] = -INFINITY; }
        __syncthreads();
    }

    {
        const int cand = tid >> 4;
        const int l = tid & 15;
        const double* krow = Kd + (size_t)cidx[cand] * D;
        double s = 0.0;
#pragma unroll 8
        for (int j = 0; j < 64; ++j) {
            int e = l + j * 16;
            s = fma(qrow[e], krow[e], s);
        }
        s += __shfl_down(s, 8);
        s += __shfl_down(s, 4);
        s += __shfl_down(s, 2);
        s += __shfl_down(s, 1);
        if (l == 0) cscore[cand] = s;
    }
    __syncthreads();

    if (tid == 0) {
        unsigned used = 0;
        double tv[8]; int ti[8];
        for (int k = 0; k < 8; ++k) {
            int best = -1;
            for (int c = 0; c < 16; ++c) {
                if (used & (1u << c)) continue;
                if (best < 0 || cscore[c] > cscore[best] ||
                    (cscore[c] == cscore[best] && cidx[c] < cidx[best])) best = c;
            }
            used |= 1u << best;
            tv[k] = cscore[best]; ti[k] = cidx[best];
        }
        double m = tv[0], e[8], sum = 0.0;
        for (int k = 0; k < 8; ++k) { e[k] = exp((tv[k] - m) / TEMP); sum += e[k]; }
        const size_t row = (size_t)batch * P + p;
        for (int k = 0; k < 8; ++k) {
            float wk = (float)(e[k] / sum);
            wts[k] = wk; topi_s[k] = ti[k];
            routes_out[row * 8 + k]  = (float)ti[k];
            weights_out[row * 8 + k] = wk;
        }
    }
    __syncthreads();

    float4 a = {0.f, 0.f, 0.f, 0.f};
#pragma unroll
    for (int k = 0; k < 8; ++k) {
        const float4 v4 = ((const float4*)(Vf + (size_t)topi_s[k] * D))[tid];
        float wk = wts[k];
        a.x = fmaf(wk, v4.x, a.x);
        a.y = fmaf(wk, v4.y, a.y);
        a.z = fmaf(wk, v4.z, a.z);
        a.w = fmaf(wk, v4.w, a.w);
    }
    ((float4*)(feat_out + ((size_t)batch * P + p) * D))[tid] = a;
}

extern "C" void kernel_launch(void* const* d_in, const int* in_sizes, int n_in,
                              void* d_out, int out_size, void* d_ws, size_t ws_size,
                              hipStream_t stream)
{
    const float* x  = (const float*)d_in[0];  // (4,2049,1024)
    const float* Wq = (const float*)d_in[1];
    const float* bq = (const float*)d_in[2];
    const float* Wk = (const float*)d_in[3];
    const float* bk = (const float*)d_in[4];
    const float* Wv = (const float*)d_in[5];
    const float* bv = (const float*)d_in[6];

    const int B = 4, P = 2048, D = 1024;
    const size_t PD = (size_t)P * D;

    double* Qd   = (double*)d_ws;             // P*D f64
    double* Kd   = Qd + PD;                   // P*D f64
    double* xsc  = Kd + PD;                   // 2048
    double* wqsc = xsc + 2048;                // 1024
    double* wksc = wqsc + 1024;               // 1024
    float*  Qf   = (float*)(wksc + 1024);     // P*D f32
    float*  Kf   = Qf + PD;
    float*  Vf   = Kf + PD;
    float*  Sf   = Vf + PD;                   // P*P f32
    signed char* Xl  = (signed char*)(Sf + (size_t)P * P);  // 5*P*D
    signed char* Wql = Xl + 5 * PD;                          // 5*D*D
    signed char* Wkl = Wql + 5 * (size_t)D * D;

    float* out     = (float*)d_out;
    float* routes  = out;
    float* weights = out + (size_t)B * P * 8;
    float* feat    = out + (size_t)B * P * 16;

    dim3 blk(256);
    quantize_rows<<<dim3(1024), blk, 0, stream>>>(Wq, Wql, (long)D * D, wqsc);
    quantize_rows<<<dim3(1024), blk, 0, stream>>>(Wk, Wkl, (long)D * D, wksc);

    for (int b = 0; b < B; ++b) {
        const float* xb = x + ((size_t)b * 2049 + 1) * D;  // rows 1..2048 contiguous
        quantize_rows<<<dim3(P), blk, 0, stream>>>(xb, Xl, (long)P * D, xsc);
        gemm_i8qk<<<dim3(16, 32, 2), blk, 0, stream>>>(Xl, Wql, Wkl, xsc, wqsc, wksc,
                                                       bq, bk, Qd, Kd);
        gemm_bf16<1><<<dim3(8, 16), blk, 0, stream>>>(xb, Wv, bv, Vf, P, D, D);
        l2norm_f64f32<<<dim3(P), blk, 0, stream>>>(Qd, Qf);
        l2norm_f64f32<<<dim3(P), blk, 0, stream>>>(Kd, Kf);
        gemm_bf16<0><<<dim3(16, 16), blk, 0, stream>>>(Qf, Kf, nullptr, Sf, P, P, D);
        topk_route<<<dim3(P), blk, 0, stream>>>(Sf, Qd, Kd, Vf, routes, weights, feat, b);
    }
}

// Round 9
// 1323.729 us; speedup vs baseline: 2.1014x; 1.0561x over previous
//
#include <hip/hip_runtime.h>
#include <hip/hip_bf16.h>
#include <math.h>

#define TEMP 0.1

typedef float f4 __attribute__((ext_vector_type(4)));
typedef short s8v __attribute__((ext_vector_type(8)));
typedef int   i4v __attribute__((ext_vector_type(4)));

__device__ inline short f2bf(float f) {
    __hip_bfloat16 h = __float2bfloat16(f);
    return *reinterpret_cast<short*>(&h);
}
__device__ inline float bf2f(short s) {
    __hip_bfloat16 h = *reinterpret_cast<__hip_bfloat16*>(&s);
    return __bfloat162float(h);
}

// ---------- quantize rows of length 1024 to 5 balanced int8 limbs (R5-proven) ----------
__global__ __launch_bounds__(256) void quantize_rows(
    const float* __restrict__ src, signed char* __restrict__ limbs,
    long plane_stride, double* __restrict__ scale)
{
    const int row = blockIdx.x, tid = threadIdx.x;
    const float4 v = ((const float4*)(src + (size_t)row * 1024))[tid];
    float m = fmaxf(fmaxf(fabsf(v.x), fabsf(v.y)), fmaxf(fabsf(v.z), fabsf(v.w)));
#pragma unroll
    for (int off = 32; off > 0; off >>= 1) m = fmaxf(m, __shfl_down(m, off));
    __shared__ float wmax[4];
    __shared__ int ssig;
    if ((tid & 63) == 0) wmax[tid >> 6] = m;
    __syncthreads();
    if (tid == 0) {
        float rm = fmaxf(fmaxf(wmax[0], wmax[1]), fmaxf(wmax[2], wmax[3]));
        int sig = (rm > 0.f) ? (37 - ilogbf(rm)) : 0;
        ssig = sig;
        scale[row] = ldexp(1.0, -sig);
    }
    __syncthreads();
    const double s2 = ldexp(1.0, ssig);
    float xs[4] = {v.x, v.y, v.z, v.w};
    signed char out[5][4];
#pragma unroll
    for (int e = 0; e < 4; ++e) {
        long X = __double2ll_rn((double)xs[e] * s2);
#pragma unroll
        for (int l = 0; l < 4; ++l) {
            int d = (int)(((X + 128) & 255) - 128);
            out[l][e] = (signed char)d;
            X = (X - d) >> 8;
        }
        out[4][e] = (signed char)X;
    }
#pragma unroll
    for (int l = 0; l < 5; ++l)
        *(char4*)&limbs[(size_t)l * plane_stride + (size_t)row * 1024 + tid * 4] =
            *(char4*)&out[l][0];
}

// ---------- exact-precision projection via i8 MFMA on limb planes (R5-proven) ----------
__global__ __launch_bounds__(256) void gemm_i8qk(
    const signed char* __restrict__ Xl,
    const signed char* __restrict__ Wql,
    const signed char* __restrict__ Wkl,
    const double* __restrict__ xsc,
    const double* __restrict__ wqsc, const double* __restrict__ wksc,
    const float* __restrict__ bq, const float* __restrict__ bk,
    double* __restrict__ Qd, double* __restrict__ Kd)
{
    const int K = 1024, N = 1024;
    const long MK = 2048L * 1024, NK = 1024L * 1024;
    const signed char* Wl = blockIdx.z ? Wkl : Wql;
    const double* wsc = blockIdx.z ? wksc : wqsc;
    const float* bias = blockIdx.z ? bk : bq;
    double* C = blockIdx.z ? Kd : Qd;

    __shared__ __align__(16) signed char Asm[5][64][80];
    __shared__ __align__(16) signed char Bsm[5][64][80];

    const int tid  = threadIdx.x;
    const int lane = tid & 63, wave = tid >> 6;
    const int wm = wave >> 1, wn = wave & 1;
    const int quad = lane >> 4, l16 = lane & 15;
    const int m0 = blockIdx.y * 64, n0 = blockIdx.x * 64;

    const int srow = tid >> 2, skq = (tid & 3) * 16;
    const signed char* ap = Xl + (size_t)(m0 + srow) * K + skq;
    const signed char* bp = Wl + (size_t)(n0 + srow) * K + skq;

    i4v acc[6][2][2] = {};

    for (int k0 = 0; k0 < K; k0 += 64) {
        i4v at[5], bt[5];
#pragma unroll
        for (int l = 0; l < 5; ++l) {
            at[l] = *(const i4v*)(ap + l * MK + k0);
            bt[l] = *(const i4v*)(bp + l * NK + k0);
        }
        __syncthreads();
#pragma unroll
        for (int l = 0; l < 5; ++l) {
            *(i4v*)&Asm[l][srow][skq] = at[l];
            *(i4v*)&Bsm[l][srow][skq] = bt[l];
        }
        __syncthreads();

        i4v bF[5][2];
#pragma unroll
        for (int j = 0; j < 5; ++j)
#pragma unroll
            for (int nt = 0; nt < 2; ++nt)
                bF[j][nt] = *(const i4v*)&Bsm[j][wn * 32 + nt * 16 + l16][quad * 16];

#pragma unroll
        for (int i = 0; i < 5; ++i) {
            i4v a0 = *(const i4v*)&Asm[i][wm * 32 +      l16][quad * 16];
            i4v a1 = *(const i4v*)&Asm[i][wm * 32 + 16 + l16][quad * 16];
#pragma unroll
            for (int j = 0; j < 5; ++j) {
                if (i + j < 3) continue;
                const int s = i + j - 3;
                acc[s][0][0] = __builtin_amdgcn_mfma_i32_16x16x64_i8(a0, bF[j][0], acc[s][0][0], 0, 0, 0);
                acc[s][0][1] = __builtin_amdgcn_mfma_i32_16x16x64_i8(a0, bF[j][1], acc[s][0][1], 0, 0, 0);
                acc[s][1][0] = __builtin_amdgcn_mfma_i32_16x16x64_i8(a1, bF[j][0], acc[s][1][0], 0, 0, 0);
                acc[s][1][1] = __builtin_amdgcn_mfma_i32_16x16x64_i8(a1, bF[j][1], acc[s][1][1], 0, 0, 0);
            }
        }
    }

    const double wt0 = ldexp(1.0, 24), wt1 = ldexp(1.0, 32), wt2 = ldexp(1.0, 40);
    const double wt3 = ldexp(1.0, 48), wt4 = ldexp(1.0, 56), wt5 = ldexp(1.0, 64);
#pragma unroll
    for (int mt = 0; mt < 2; ++mt)
#pragma unroll
        for (int nt = 0; nt < 2; ++nt)
#pragma unroll
            for (int r = 0; r < 4; ++r) {
                int row = m0 + wm * 32 + mt * 16 + quad * 4 + r;
                int col = n0 + wn * 32 + nt * 16 + l16;
                double dsum = wt0 * (double)acc[0][mt][nt][r]
                            + wt1 * (double)acc[1][mt][nt][r]
                            + wt2 * (double)acc[2][mt][nt][r]
                            + wt3 * (double)acc[3][mt][nt][r]
                            + wt4 * (double)acc[4][mt][nt][r]
                            + wt5 * (double)acc[5][mt][nt][r];
                C[(size_t)row * N + col] = dsum * xsc[row] * wsc[col] + (double)bias[col];
            }
}

// ---------------- bf16 MFMA GEMM (128 tile, hi/lo split) — R4-proven, V proj ----
template <int SPLIT>
__global__ __launch_bounds__(256) void gemm_bf16(
    const float* __restrict__ A, const float* __restrict__ B,
    const float* __restrict__ bias, float* __restrict__ C,
    int M, int N, int K)
{
    __shared__ short Ah[128][40];
    __shared__ short Bh[128][40];
    __shared__ short Al[SPLIT ? 128 : 1][40];
    __shared__ short Bl[SPLIT ? 128 : 1][40];

    const int tid  = threadIdx.x;
    const int lane = tid & 63, wave = tid >> 6;
    const int wm = wave >> 1, wn = wave & 1;
    const int quad = lane >> 4, l16 = lane & 15;
    const int m0 = blockIdx.y * 128, n0 = blockIdx.x * 128;

    const int srow = tid >> 1, sco = (tid & 1) * 16;
    const float* ap = A + (size_t)(m0 + srow) * K + sco;
    const float* bp = B + (size_t)(n0 + srow) * K + sco;

    f4 acc[4][4] = {};

    for (int k0 = 0; k0 < K; k0 += 32) {
        float av[16], bv[16];
#pragma unroll
        for (int i = 0; i < 4; ++i) {
            *(float4*)&av[i * 4] = *(const float4*)(ap + k0 + i * 4);
            *(float4*)&bv[i * 4] = *(const float4*)(bp + k0 + i * 4);
        }
        __align__(16) short ahv[16], bhv[16], alv[16], blv[16];
#pragma unroll
        for (int i = 0; i < 16; ++i) {
            short h = f2bf(av[i]); ahv[i] = h;
            if (SPLIT) alv[i] = f2bf(av[i] - bf2f(h));
            short g = f2bf(bv[i]); bhv[i] = g;
            if (SPLIT) blv[i] = f2bf(bv[i] - bf2f(g));
        }
        __syncthreads();
        *(s8v*)&Ah[srow][sco]     = *(s8v*)&ahv[0];
        *(s8v*)&Ah[srow][sco + 8] = *(s8v*)&ahv[8];
        *(s8v*)&Bh[srow][sco]     = *(s8v*)&bhv[0];
        *(s8v*)&Bh[srow][sco + 8] = *(s8v*)&bhv[8];
        if (SPLIT) {
            *(s8v*)&Al[srow][sco]     = *(s8v*)&alv[0];
            *(s8v*)&Al[srow][sco + 8] = *(s8v*)&alv[8];
            *(s8v*)&Bl[srow][sco]     = *(s8v*)&blv[0];
            *(s8v*)&Bl[srow][sco + 8] = *(s8v*)&blv[8];
        }
        __syncthreads();

        s8v af[4], bfr[4], afl[4], bfl[4];
#pragma unroll
        for (int t = 0; t < 4; ++t) {
            af[t]  = *(s8v*)&Ah[wm * 64 + t * 16 + l16][quad * 8];
            bfr[t] = *(s8v*)&Bh[wn * 64 + t * 16 + l16][quad * 8];
            if (SPLIT) {
                afl[t] = *(s8v*)&Al[wm * 64 + t * 16 + l16][quad * 8];
                bfl[t] = *(s8v*)&Bl[wn * 64 + t * 16 + l16][quad * 8];
            }
        }
#pragma unroll
        for (int mt = 0; mt < 4; ++mt)
#pragma unroll
            for (int nt = 0; nt < 4; ++nt) {
                acc[mt][nt] = __builtin_amdgcn_mfma_f32_16x16x32_bf16(
                    af[mt], bfr[nt], acc[mt][nt], 0, 0, 0);
                if (SPLIT) {
                    acc[mt][nt] = __builtin_amdgcn_mfma_f32_16x16x32_bf16(
                        af[mt], bfl[nt], acc[mt][nt], 0, 0, 0);
                    acc[mt][nt] = __builtin_amdgcn_mfma_f32_16x16x32_bf16(
                        afl[mt], bfr[nt], acc[mt][nt], 0, 0, 0);
                }
            }
    }

#pragma unroll
    for (int mt = 0; mt < 4; ++mt)
#pragma unroll
        for (int nt = 0; nt < 4; ++nt)
#pragma unroll
            for (int r = 0; r < 4; ++r) {
                int row = m0 + wm * 64 + mt * 16 + quad * 4 + r;
                int col = n0 + wn * 64 + nt * 16 + l16;
                float v = acc[mt][nt][r];
                if (bias) v += bias[col];
                C[(size_t)row * N + col] = v;
            }
}

// ------- score GEMM: 64x64 tile, bf16 inputs, fp32 out (kept from R6/R7) -------
__global__ __launch_bounds__(256) void gemm_score(
    const short* __restrict__ Qh, const short* __restrict__ Kh,
    float* __restrict__ C)
{
    const int K = 1024, N = 2048;
    __shared__ short As[64][40];
    __shared__ short Bs[64][40];
    const int tid = threadIdx.x, lane = tid & 63, wave = tid >> 6;
    const int wm = wave >> 1, wn = wave & 1;
    const int quad = lane >> 4, l16 = lane & 15;
    const int m0 = blockIdx.y * 64, n0 = blockIdx.x * 64;
    const int srow = tid >> 2, sco = (tid & 3) * 8;
    const short* ap = Qh + (size_t)(m0 + srow) * K + sco;
    const short* bp = Kh + (size_t)(n0 + srow) * K + sco;

    f4 acc[2][2] = {};
    for (int k0 = 0; k0 < K; k0 += 32) {
        s8v a8 = *(const s8v*)(ap + k0);
        s8v b8 = *(const s8v*)(bp + k0);
        __syncthreads();
        *(s8v*)&As[srow][sco] = a8;
        *(s8v*)&Bs[srow][sco] = b8;
        __syncthreads();
        s8v af[2], bf[2];
#pragma unroll
        for (int t = 0; t < 2; ++t) {
            af[t] = *(s8v*)&As[wm * 32 + t * 16 + l16][quad * 8];
            bf[t] = *(s8v*)&Bs[wn * 32 + t * 16 + l16][quad * 8];
        }
#pragma unroll
        for (int mt = 0; mt < 2; ++mt)
#pragma unroll
            for (int nt = 0; nt < 2; ++nt)
                acc[mt][nt] = __builtin_amdgcn_mfma_f32_16x16x32_bf16(
                    af[mt], bf[nt], acc[mt][nt], 0, 0, 0);
    }
#pragma unroll
    for (int mt = 0; mt < 2; ++mt)
#pragma unroll
        for (int nt = 0; nt < 2; ++nt)
#pragma unroll
            for (int r = 0; r < 4; ++r) {
                int row = m0 + wm * 32 + mt * 16 + quad * 4 + r;
                int col = n0 + wn * 32 + nt * 16 + l16;
                C[(size_t)row * N + col] = acc[mt][nt][r];
            }
}

// ------- fp64 L2 normalize rows (in place) + bf16 copy (aligned store fix) -------
__global__ __launch_bounds__(256) void l2norm_f64bf16(
    double* __restrict__ d, short* __restrict__ h)
{
    const int row = blockIdx.x;
    const int tid = threadIdx.x;
    double* p = d + (size_t)row * 1024 + tid * 4;
    double v0 = p[0], v1 = p[1], v2 = p[2], v3 = p[3];
    double s = v0 * v0 + v1 * v1 + v2 * v2 + v3 * v3;
#pragma unroll
    for (int off = 32; off > 0; off >>= 1) s += __shfl_down(s, off);
    __shared__ double ws[5];
    if ((tid & 63) == 0) ws[tid >> 6] = s;
    __syncthreads();
    if (tid == 0) ws[4] = fmax(sqrt(ws[0] + ws[1] + ws[2] + ws[3]), 1e-12);
    __syncthreads();
    double n = ws[4];
    double o0 = v0 / n, o1 = v1 / n, o2 = v2 / n, o3 = v3 / n;
    p[0] = o0; p[1] = o1; p[2] = o2; p[3] = o3;
    __align__(8) short hv[4] = {f2bf((float)o0), f2bf((float)o1),
                                f2bf((float)o2), f2bf((float)o3)};
    *(short4*)&h[(size_t)row * 1024 + tid * 4] = *(short4*)hv;
}

// ------- fp32 top-16 (serial argmax, R5-proven) + fp64 rerank + route -------
__global__ __launch_bounds__(256) void topk_route(
    const float*  __restrict__ S,
    const double* __restrict__ Qd,
    const double* __restrict__ Kd,
    const float*  __restrict__ Vf,
    float* __restrict__ routes_out,
    float* __restrict__ weights_out,
    float* __restrict__ feat_out,
    int batch)
{
    const int P = 2048, D = 1024;
    __shared__ float  sc[2048];
    __shared__ double qrow[1024];
    __shared__ float  rval[256];
    __shared__ int    ridx[256];
    __shared__ int    cidx[16];
    __shared__ double cscore[16];
    __shared__ int    topi_s[8];
    __shared__ float  wts[8];

    const int p = blockIdx.x;
    const int tid = threadIdx.x;

    const float4* sr4 = (const float4*)(S + (size_t)p * P);
    ((float4*)sc)[tid]       = sr4[tid];
    ((float4*)sc)[tid + 256] = sr4[tid + 256];
    {
        const double* q = Qd + (size_t)p * D + tid * 4;
        qrow[tid * 4 + 0] = q[0]; qrow[tid * 4 + 1] = q[1];
        qrow[tid * 4 + 2] = q[2]; qrow[tid * 4 + 3] = q[3];
    }
    __syncthreads();
    if (tid == 0) sc[p] = -1e30f;
    __syncthreads();

    for (int it = 0; it < 16; ++it) {
        float bv = -INFINITY; int bi = 0x7fffffff;
#pragma unroll
        for (int r = 0; r < 8; ++r) {
            int j = tid + r * 256;
            float v = sc[j];
            if (v > bv || (v == bv && j < bi)) { bv = v; bi = j; }
        }
        rval[tid] = bv; ridx[tid] = bi;
        __syncthreads();
        for (int off = 128; off > 0; off >>= 1) {
            if (tid < off) {
                float ov = rval[tid + off]; int oi = ridx[tid + off];
                if (ov > rval[tid] || (ov == rval[tid] && oi < ridx[tid])) {
                    rval[tid] = ov; ridx[tid] = oi;
                }
            }
            __syncthreads();
        }
        if (tid == 0) { cidx[it] = ridx[0]; sc[ridx[0]] = -INFINITY; }
        __syncthreads();
    }

    {
        const int cand = tid >> 4;
        const int l = tid & 15;
        const double* krow = Kd + (size_t)cidx[cand] * D;
        double s = 0.0;
#pragma unroll 8
        for (int j = 0; j < 64; ++j) {
            int e = l + j * 16;
            s = fma(qrow[e], krow[e], s);
        }
        s += __shfl_down(s, 8);
        s += __shfl_down(s, 4);
        s += __shfl_down(s, 2);
        s += __shfl_down(s, 1);
        if (l == 0) cscore[cand] = s;
    }
    __syncthreads();

    if (tid == 0) {
        unsigned used = 0;
        double tv[8]; int ti[8];
        for (int k = 0; k < 8; ++k) {
            int best = -1;
            for (int c = 0; c < 16; ++c) {
                if (used & (1u << c)) continue;
                if (best < 0 || cscore[c] > cscore[best] ||
                    (cscore[c] == cscore[best] && cidx[c] < cidx[best])) best = c;
            }
            used |= 1u << best;
            tv[k] = cscore[best]; ti[k] = cidx[best];
        }
        double m = tv[0], e[8], sum = 0.0;
        for (int k = 0; k < 8; ++k) { e[k] = exp((tv[k] - m) / TEMP); sum += e[k]; }
        const size_t row = (size_t)batch * P + p;
        for (int k = 0; k < 8; ++k) {
            float wk = (float)(e[k] / sum);
            wts[k] = wk; topi_s[k] = ti[k];
            routes_out[row * 8 + k]  = (float)ti[k];
            weights_out[row * 8 + k] = wk;
        }
    }
    __syncthreads();

    float4 a = {0.f, 0.f, 0.f, 0.f};
#pragma unroll
    for (int k = 0; k < 8; ++k) {
        const float4 v4 = ((const float4*)(Vf + (size_t)topi_s[k] * D))[tid];
        float wk = wts[k];
        a.x = fmaf(wk, v4.x, a.x);
        a.y = fmaf(wk, v4.y, a.y);
        a.z = fmaf(wk, v4.z, a.z);
        a.w = fmaf(wk, v4.w, a.w);
    }
    ((float4*)(feat_out + ((size_t)batch * P + p) * D))[tid] = a;
}

extern "C" void kernel_launch(void* const* d_in, const int* in_sizes, int n_in,
                              void* d_out, int out_size, void* d_ws, size_t ws_size,
                              hipStream_t stream)
{
    const float* x  = (const float*)d_in[0];  // (4,2049,1024)
    const float* Wq = (const float*)d_in[1];
    const float* bq = (const float*)d_in[2];
    const float* Wk = (const float*)d_in[3];
    const float* bk = (const float*)d_in[4];
    const float* Wv = (const float*)d_in[5];
    const float* bv = (const float*)d_in[6];

    const int B = 4, P = 2048, D = 1024;
    const size_t PD = (size_t)P * D;

    double* Qd   = (double*)d_ws;             // P*D f64
    double* Kd   = Qd + PD;
    double* xsc  = Kd + PD;                   // 2048
    double* wqsc = xsc + 2048;                // 1024
    double* wksc = wqsc + 1024;               // 1024
    short*  Qh   = (short*)(wksc + 1024);     // P*D bf16
    short*  Kh   = Qh + PD;
    float*  Vf   = (float*)(Kh + PD);         // P*D f32
    float*  Sf   = Vf + PD;                   // P*P f32
    signed char* Xl  = (signed char*)(Sf + (size_t)P * P);  // 5*P*D
    signed char* Wql = Xl + 5 * PD;                          // 5*D*D
    signed char* Wkl = Wql + 5 * (size_t)D * D;

    float* out     = (float*)d_out;
    float* routes  = out;
    float* weights = out + (size_t)B * P * 8;
    float* feat    = out + (size_t)B * P * 16;

    dim3 blk(256);
    quantize_rows<<<dim3(1024), blk, 0, stream>>>(Wq, Wql, (long)D * D, wqsc);
    quantize_rows<<<dim3(1024), blk, 0, stream>>>(Wk, Wkl, (long)D * D, wksc);

    for (int b = 0; b < B; ++b) {
        const float* xb = x + ((size_t)b * 2049 + 1) * D;  // rows 1..2048 contiguous
        quantize_rows<<<dim3(P), blk, 0, stream>>>(xb, Xl, (long)P * D, xsc);
        gemm_i8qk<<<dim3(16, 32, 2), blk, 0, stream>>>(Xl, Wql, Wkl, xsc, wqsc, wksc,
                                                       bq, bk, Qd, Kd);
        gemm_bf16<1><<<dim3(8, 16), blk, 0, stream>>>(xb, Wv, bv, Vf, P, D, D);
        l2norm_f64bf16<<<dim3(P), blk, 0, stream>>>(Qd, Qh);
        l2norm_f64bf16<<<dim3(P), blk, 0, stream>>>(Kd, Kh);
        gemm_score<<<dim3(32, 32), blk, 0, stream>>>(Qh, Kh, Sf);
        topk_route<<<dim3(P), blk, 0, stream>>>(Sf, Qd, Kd, Vf, routes, weights, feat, b);
    }
}

// Round 10
// 1102.814 us; speedup vs baseline: 2.5223x; 1.2003x over previous
//
#include <hip/hip_runtime.h>
#include <hip/hip_bf16.h>
#include <math.h>

#define TEMP 0.1

typedef float f4 __attribute__((ext_vector_type(4)));
typedef short s8v __attribute__((ext_vector_type(8)));
typedef int   i4v __attribute__((ext_vector_type(4)));

__device__ inline short f2bf(float f) {
    __hip_bfloat16 h = __float2bfloat16(f);
    return *reinterpret_cast<short*>(&h);
}
__device__ inline float bf2f(short s) {
    __hip_bfloat16 h = *reinterpret_cast<__hip_bfloat16*>(&s);
    return __bfloat162float(h);
}

// ---------- quantize rows of length 1024 to 5 balanced int8 limbs (R5-proven) ----------
__global__ __launch_bounds__(256) void quantize_rows(
    const float* __restrict__ src, signed char* __restrict__ limbs,
    long plane_stride, double* __restrict__ scale)
{
    const int row = blockIdx.x, tid = threadIdx.x;
    const float4 v = ((const float4*)(src + (size_t)row * 1024))[tid];
    float m = fmaxf(fmaxf(fabsf(v.x), fabsf(v.y)), fmaxf(fabsf(v.z), fabsf(v.w)));
#pragma unroll
    for (int off = 32; off > 0; off >>= 1) m = fmaxf(m, __shfl_down(m, off));
    __shared__ float wmax[4];
    __shared__ int ssig;
    if ((tid & 63) == 0) wmax[tid >> 6] = m;
    __syncthreads();
    if (tid == 0) {
        float rm = fmaxf(fmaxf(wmax[0], wmax[1]), fmaxf(wmax[2], wmax[3]));
        int sig = (rm > 0.f) ? (37 - ilogbf(rm)) : 0;
        ssig = sig;
        scale[row] = ldexp(1.0, -sig);
    }
    __syncthreads();
    const double s2 = ldexp(1.0, ssig);
    float xs[4] = {v.x, v.y, v.z, v.w};
    signed char out[5][4];
#pragma unroll
    for (int e = 0; e < 4; ++e) {
        long X = __double2ll_rn((double)xs[e] * s2);
#pragma unroll
        for (int l = 0; l < 4; ++l) {
            int d = (int)(((X + 128) & 255) - 128);
            out[l][e] = (signed char)d;
            X = (X - d) >> 8;
        }
        out[4][e] = (signed char)X;
    }
#pragma unroll
    for (int l = 0; l < 5; ++l)
        *(char4*)&limbs[(size_t)l * plane_stride + (size_t)row * 1024 + tid * 4] =
            *(char4*)&out[l][0];
}

// ---------- exact-precision projection via i8 MFMA (R5-proven math + prefetch) ----------
__global__ __launch_bounds__(256) void gemm_i8qk(
    const signed char* __restrict__ Xl,
    const signed char* __restrict__ Wql,
    const signed char* __restrict__ Wkl,
    const double* __restrict__ xsc,
    const double* __restrict__ wqsc, const double* __restrict__ wksc,
    const float* __restrict__ bq, const float* __restrict__ bk,
    double* __restrict__ Qd, double* __restrict__ Kd)
{
    const int K = 1024, N = 1024;
    const long MK = 2048L * 1024, NK = 1024L * 1024;
    const signed char* Wl = blockIdx.z ? Wkl : Wql;
    const double* wsc = blockIdx.z ? wksc : wqsc;
    const float* bias = blockIdx.z ? bk : bq;
    double* C = blockIdx.z ? Kd : Qd;

    __shared__ __align__(16) signed char Asm[5][64][80];
    __shared__ __align__(16) signed char Bsm[5][64][80];

    const int tid  = threadIdx.x;
    const int lane = tid & 63, wave = tid >> 6;
    const int wm = wave >> 1, wn = wave & 1;
    const int quad = lane >> 4, l16 = lane & 15;
    const int m0 = blockIdx.y * 64, n0 = blockIdx.x * 64;

    const int srow = tid >> 2, skq = (tid & 3) * 16;
    const signed char* ap = Xl + (size_t)(m0 + srow) * K + skq;
    const signed char* bp = Wl + (size_t)(n0 + srow) * K + skq;

    i4v acc[6][2][2] = {};

    // prefetch first K-chunk
    i4v at[5], bt[5];
#pragma unroll
    for (int l = 0; l < 5; ++l) {
        at[l] = *(const i4v*)(ap + l * MK);
        bt[l] = *(const i4v*)(bp + l * NK);
    }

    for (int k0 = 0; k0 < K; k0 += 64) {
        __syncthreads();
#pragma unroll
        for (int l = 0; l < 5; ++l) {
            *(i4v*)&Asm[l][srow][skq] = at[l];
            *(i4v*)&Bsm[l][srow][skq] = bt[l];
        }
        __syncthreads();

        // prefetch next chunk — latency hidden behind the 76 MFMAs below
        if (k0 + 64 < K) {
#pragma unroll
            for (int l = 0; l < 5; ++l) {
                at[l] = *(const i4v*)(ap + l * MK + k0 + 64);
                bt[l] = *(const i4v*)(bp + l * NK + k0 + 64);
            }
        }

        i4v bF[5][2];
#pragma unroll
        for (int j = 0; j < 5; ++j)
#pragma unroll
            for (int nt = 0; nt < 2; ++nt)
                bF[j][nt] = *(const i4v*)&Bsm[j][wn * 32 + nt * 16 + l16][quad * 16];

#pragma unroll
        for (int i = 0; i < 5; ++i) {
            i4v a0 = *(const i4v*)&Asm[i][wm * 32 +      l16][quad * 16];
            i4v a1 = *(const i4v*)&Asm[i][wm * 32 + 16 + l16][quad * 16];
#pragma unroll
            for (int j = 0; j < 5; ++j) {
                if (i + j < 3) continue;
                const int s = i + j - 3;
                acc[s][0][0] = __builtin_amdgcn_mfma_i32_16x16x64_i8(a0, bF[j][0], acc[s][0][0], 0, 0, 0);
                acc[s][0][1] = __builtin_amdgcn_mfma_i32_16x16x64_i8(a0, bF[j][1], acc[s][0][1], 0, 0, 0);
                acc[s][1][0] = __builtin_amdgcn_mfma_i32_16x16x64_i8(a1, bF[j][0], acc[s][1][0], 0, 0, 0);
                acc[s][1][1] = __builtin_amdgcn_mfma_i32_16x16x64_i8(a1, bF[j][1], acc[s][1][1], 0, 0, 0);
            }
        }
    }

    const double wt0 = ldexp(1.0, 24), wt1 = ldexp(1.0, 32), wt2 = ldexp(1.0, 40);
    const double wt3 = ldexp(1.0, 48), wt4 = ldexp(1.0, 56), wt5 = ldexp(1.0, 64);
#pragma unroll
    for (int mt = 0; mt < 2; ++mt)
#pragma unroll
        for (int nt = 0; nt < 2; ++nt)
#pragma unroll
            for (int r = 0; r < 4; ++r) {
                int row = m0 + wm * 32 + mt * 16 + quad * 4 + r;
                int col = n0 + wn * 32 + nt * 16 + l16;
                double dsum = wt0 * (double)acc[0][mt][nt][r]
                            + wt1 * (double)acc[1][mt][nt][r]
                            + wt2 * (double)acc[2][mt][nt][r]
                            + wt3 * (double)acc[3][mt][nt][r]
                            + wt4 * (double)acc[4][mt][nt][r]
                            + wt5 * (double)acc[5][mt][nt][r];
                C[(size_t)row * N + col] = dsum * xsc[row] * wsc[col] + (double)bias[col];
            }
}

// ------- V projection: 64x64 tile, split-bf16 (same per-element math as R4) -------
__global__ __launch_bounds__(256) void gemm_v64(
    const float* __restrict__ A, const float* __restrict__ B,
    const float* __restrict__ bias, float* __restrict__ C)
{
    const int K = 1024, N = 1024;
    __shared__ short Ah[64][40];
    __shared__ short Al[64][40];
    __shared__ short Bh[64][40];
    __shared__ short Bl[64][40];

    const int tid = threadIdx.x, lane = tid & 63, wave = tid >> 6;
    const int wm = wave >> 1, wn = wave & 1;
    const int quad = lane >> 4, l16 = lane & 15;
    const int m0 = blockIdx.y * 64, n0 = blockIdx.x * 64;
    const int srow = tid >> 2, sco = (tid & 3) * 8;
    const float* ap = A + (size_t)(m0 + srow) * K + sco;
    const float* bp = B + (size_t)(n0 + srow) * K + sco;

    f4 acc[2][2] = {};
    for (int k0 = 0; k0 < K; k0 += 32) {
        float av[8], bv[8];
        *(float4*)&av[0] = *(const float4*)(ap + k0);
        *(float4*)&av[4] = *(const float4*)(ap + k0 + 4);
        *(float4*)&bv[0] = *(const float4*)(bp + k0);
        *(float4*)&bv[4] = *(const float4*)(bp + k0 + 4);
        __align__(16) short ahv[8], alv[8], bhv[8], blv[8];
#pragma unroll
        for (int i = 0; i < 8; ++i) {
            short h = f2bf(av[i]); ahv[i] = h; alv[i] = f2bf(av[i] - bf2f(h));
            short g = f2bf(bv[i]); bhv[i] = g; blv[i] = f2bf(bv[i] - bf2f(g));
        }
        __syncthreads();
        *(s8v*)&Ah[srow][sco] = *(s8v*)&ahv[0];
        *(s8v*)&Al[srow][sco] = *(s8v*)&alv[0];
        *(s8v*)&Bh[srow][sco] = *(s8v*)&bhv[0];
        *(s8v*)&Bl[srow][sco] = *(s8v*)&blv[0];
        __syncthreads();

        s8v af[2], afl[2], bf[2], bfl[2];
#pragma unroll
        for (int t = 0; t < 2; ++t) {
            af[t]  = *(s8v*)&Ah[wm * 32 + t * 16 + l16][quad * 8];
            afl[t] = *(s8v*)&Al[wm * 32 + t * 16 + l16][quad * 8];
            bf[t]  = *(s8v*)&Bh[wn * 32 + t * 16 + l16][quad * 8];
            bfl[t] = *(s8v*)&Bl[wn * 32 + t * 16 + l16][quad * 8];
        }
#pragma unroll
        for (int mt = 0; mt < 2; ++mt)
#pragma unroll
            for (int nt = 0; nt < 2; ++nt) {
                acc[mt][nt] = __builtin_amdgcn_mfma_f32_16x16x32_bf16(af[mt],  bf[nt],  acc[mt][nt], 0, 0, 0);
                acc[mt][nt] = __builtin_amdgcn_mfma_f32_16x16x32_bf16(af[mt],  bfl[nt], acc[mt][nt], 0, 0, 0);
                acc[mt][nt] = __builtin_amdgcn_mfma_f32_16x16x32_bf16(afl[mt], bf[nt],  acc[mt][nt], 0, 0, 0);
            }
    }
#pragma unroll
    for (int mt = 0; mt < 2; ++mt)
#pragma unroll
        for (int nt = 0; nt < 2; ++nt)
#pragma unroll
            for (int r = 0; r < 4; ++r) {
                int row = m0 + wm * 32 + mt * 16 + quad * 4 + r;
                int col = n0 + wn * 32 + nt * 16 + l16;
                C[(size_t)row * N + col] = acc[mt][nt][r] + bias[col];
            }
}

// ------- score GEMM: 64x64 tile, bf16 inputs, fp32 out (R8-proven) -------
__global__ __launch_bounds__(256) void gemm_score(
    const short* __restrict__ Qh, const short* __restrict__ Kh,
    float* __restrict__ C)
{
    const int K = 1024, N = 2048;
    __shared__ short As[64][40];
    __shared__ short Bs[64][40];
    const int tid = threadIdx.x, lane = tid & 63, wave = tid >> 6;
    const int wm = wave >> 1, wn = wave & 1;
    const int quad = lane >> 4, l16 = lane & 15;
    const int m0 = blockIdx.y * 64, n0 = blockIdx.x * 64;
    const int srow = tid >> 2, sco = (tid & 3) * 8;
    const short* ap = Qh + (size_t)(m0 + srow) * K + sco;
    const short* bp = Kh + (size_t)(n0 + srow) * K + sco;

    f4 acc[2][2] = {};
    for (int k0 = 0; k0 < K; k0 += 32) {
        s8v a8 = *(const s8v*)(ap + k0);
        s8v b8 = *(const s8v*)(bp + k0);
        __syncthreads();
        *(s8v*)&As[srow][sco] = a8;
        *(s8v*)&Bs[srow][sco] = b8;
        __syncthreads();
        s8v af[2], bf[2];
#pragma unroll
        for (int t = 0; t < 2; ++t) {
            af[t] = *(s8v*)&As[wm * 32 + t * 16 + l16][quad * 8];
            bf[t] = *(s8v*)&Bs[wn * 32 + t * 16 + l16][quad * 8];
        }
#pragma unroll
        for (int mt = 0; mt < 2; ++mt)
#pragma unroll
            for (int nt = 0; nt < 2; ++nt)
                acc[mt][nt] = __builtin_amdgcn_mfma_f32_16x16x32_bf16(
                    af[mt], bf[nt], acc[mt][nt], 0, 0, 0);
    }
#pragma unroll
    for (int mt = 0; mt < 2; ++mt)
#pragma unroll
        for (int nt = 0; nt < 2; ++nt)
#pragma unroll
            for (int r = 0; r < 4; ++r) {
                int row = m0 + wm * 32 + mt * 16 + quad * 4 + r;
                int col = n0 + wn * 32 + nt * 16 + l16;
                C[(size_t)row * N + col] = acc[mt][nt][r];
            }
}

// ------- fp64 L2 normalize rows (in place) + bf16 copy (R8-proven) -------
__global__ __launch_bounds__(256) void l2norm_f64bf16(
    double* __restrict__ d, short* __restrict__ h)
{
    const int row = blockIdx.x;
    const int tid = threadIdx.x;
    double* p = d + (size_t)row * 1024 + tid * 4;
    double v0 = p[0], v1 = p[1], v2 = p[2], v3 = p[3];
    double s = v0 * v0 + v1 * v1 + v2 * v2 + v3 * v3;
#pragma unroll
    for (int off = 32; off > 0; off >>= 1) s += __shfl_down(s, off);
    __shared__ double ws[5];
    if ((tid & 63) == 0) ws[tid >> 6] = s;
    __syncthreads();
    if (tid == 0) ws[4] = fmax(sqrt(ws[0] + ws[1] + ws[2] + ws[3]), 1e-12);
    __syncthreads();
    double n = ws[4];
    double o0 = v0 / n, o1 = v1 / n, o2 = v2 / n, o3 = v3 / n;
    p[0] = o0; p[1] = o1; p[2] = o2; p[3] = o3;
    __align__(8) short hv[4] = {f2bf((float)o0), f2bf((float)o1),
                                f2bf((float)o2), f2bf((float)o3)};
    *(short4*)&h[(size_t)row * 1024 + tid * 4] = *(short4*)hv;
}

// ------- top-16 via shuffle-argmax (same exact semantics) + fp64 rerank + route -------
__global__ __launch_bounds__(256) void topk_route(
    const float*  __restrict__ S,
    const double* __restrict__ Qd,
    const double* __restrict__ Kd,
    const float*  __restrict__ Vf,
    float* __restrict__ routes_out,
    float* __restrict__ weights_out,
    float* __restrict__ feat_out,
    int batch)
{
    const int P = 2048, D = 1024;
    __shared__ float  sc[2048];
    __shared__ double qrow[1024];
    __shared__ float  wval[4];
    __shared__ int    widx[4];
    __shared__ int    cidx[16];
    __shared__ double cscore[16];
    __shared__ int    topi_s[8];
    __shared__ float  wts[8];

    const int p = blockIdx.x;
    const int tid = threadIdx.x;
    const int lane = tid & 63, wave = tid >> 6;

    const float4* sr4 = (const float4*)(S + (size_t)p * P);
    ((float4*)sc)[tid]       = sr4[tid];
    ((float4*)sc)[tid + 256] = sr4[tid + 256];
    {
        const double* q = Qd + (size_t)p * D + tid * 4;
        qrow[tid * 4 + 0] = q[0]; qrow[tid * 4 + 1] = q[1];
        qrow[tid * 4 + 2] = q[2]; qrow[tid * 4 + 3] = q[3];
    }
    __syncthreads();
    if (tid == 0) sc[p] = -1e30f;
    __syncthreads();

    for (int it = 0; it < 16; ++it) {
        float bv = -INFINITY; int bi = 0x7fffffff;
#pragma unroll
        for (int r = 0; r < 8; ++r) {
            int j = tid + r * 256;
            float v = sc[j];
            if (v > bv || (v == bv && j < bi)) { bv = v; bi = j; }
        }
        // wave-level argmax (exact compares, lowest-index tie-break)
#pragma unroll
        for (int off = 32; off > 0; off >>= 1) {
            float ov = __shfl_down(bv, off);
            int   oi = __shfl_down(bi, off);
            if (ov > bv || (ov == bv && oi < bi)) { bv = ov; bi = oi; }
        }
        if (lane == 0) { wval[wave] = bv; widx[wave] = bi; }
        __syncthreads();
        if (tid == 0) {
            float gv = wval[0]; int gi = widx[0];
#pragma unroll
            for (int w = 1; w < 4; ++w) {
                if (wval[w] > gv || (wval[w] == gv && widx[w] < gi)) {
                    gv = wval[w]; gi = widx[w];
                }
            }
            cidx[it] = gi;
            sc[gi] = -INFINITY;
        }
        __syncthreads();
    }

    {
        const int cand = tid >> 4;
        const int l = tid & 15;
        const double* krow = Kd + (size_t)cidx[cand] * D;
        double s = 0.0;
#pragma unroll 8
        for (int j = 0; j < 64; ++j) {
            int e = l + j * 16;
            s = fma(qrow[e], krow[e], s);
        }
        s += __shfl_down(s, 8);
        s += __shfl_down(s, 4);
        s += __shfl_down(s, 2);
        s += __shfl_down(s, 1);
        if (l == 0) cscore[cand] = s;
    }
    __syncthreads();

    if (tid == 0) {
        unsigned used = 0;
        double tv[8]; int ti[8];
        for (int k = 0; k < 8; ++k) {
            int best = -1;
            for (int c = 0; c < 16; ++c) {
                if (used & (1u << c)) continue;
                if (best < 0 || cscore[c] > cscore[best] ||
                    (cscore[c] == cscore[best] && cidx[c] < cidx[best])) best = c;
            }
            used |= 1u << best;
            tv[k] = cscore[best]; ti[k] = cidx[best];
        }
        double m = tv[0], e[8], sum = 0.0;
        for (int k = 0; k < 8; ++k) { e[k] = exp((tv[k] - m) / TEMP); sum += e[k]; }
        const size_t row = (size_t)batch * P + p;
        for (int k = 0; k < 8; ++k) {
            float wk = (float)(e[k] / sum);
            wts[k] = wk; topi_s[k] = ti[k];
            routes_out[row * 8 + k]  = (float)ti[k];
            weights_out[row * 8 + k] = wk;
        }
    }
    __syncthreads();

    float4 a = {0.f, 0.f, 0.f, 0.f};
#pragma unroll
    for (int k = 0; k < 8; ++k) {
        const float4 v4 = ((const float4*)(Vf + (size_t)topi_s[k] * D))[tid];
        float wk = wts[k];
        a.x = fmaf(wk, v4.x, a.x);
        a.y = fmaf(wk, v4.y, a.y);
        a.z = fmaf(wk, v4.z, a.z);
        a.w = fmaf(wk, v4.w, a.w);
    }
    ((float4*)(feat_out + ((size_t)batch * P + p) * D))[tid] = a;
}

extern "C" void kernel_launch(void* const* d_in, const int* in_sizes, int n_in,
                              void* d_out, int out_size, void* d_ws, size_t ws_size,
                              hipStream_t stream)
{
    const float* x  = (const float*)d_in[0];  // (4,2049,1024)
    const float* Wq = (const float*)d_in[1];
    const float* bq = (const float*)d_in[2];
    const float* Wk = (const float*)d_in[3];
    const float* bk = (const float*)d_in[4];
    const float* Wv = (const float*)d_in[5];
    const float* bv = (const float*)d_in[6];

    const int B = 4, P = 2048, D = 1024;
    const size_t PD = (size_t)P * D;

    double* Qd   = (double*)d_ws;             // P*D f64
    double* Kd   = Qd + PD;
    double* xsc  = Kd + PD;                   // 2048
    double* wqsc = xsc + 2048;                // 1024
    double* wksc = wqsc + 1024;               // 1024
    short*  Qh   = (short*)(wksc + 1024);     // P*D bf16
    short*  Kh   = Qh + PD;
    float*  Vf   = (float*)(Kh + PD);         // P*D f32
    float*  Sf   = Vf + PD;                   // P*P f32
    signed char* Xl  = (signed char*)(Sf + (size_t)P * P);  // 5*P*D
    signed char* Wql = Xl + 5 * PD;                          // 5*D*D
    signed char* Wkl = Wql + 5 * (size_t)D * D;

    float* out     = (float*)d_out;
    float* routes  = out;
    float* weights = out + (size_t)B * P * 8;
    float* feat    = out + (size_t)B * P * 16;

    dim3 blk(256);
    quantize_rows<<<dim3(1024), blk, 0, stream>>>(Wq, Wql, (long)D * D, wqsc);
    quantize_rows<<<dim3(1024), blk, 0, stream>>>(Wk, Wkl, (long)D * D, wksc);

    for (int b = 0; b < B; ++b) {
        const float* xb = x + ((size_t)b * 2049 + 1) * D;  // rows 1..2048 contiguous
        quantize_rows<<<dim3(P), blk, 0, stream>>>(xb, Xl, (long)P * D, xsc);
        gemm_i8qk<<<dim3(16, 32, 2), blk, 0, stream>>>(Xl, Wql, Wkl, xsc, wqsc, wksc,
                                                       bq, bk, Qd, Kd);
        gemm_v64<<<dim3(16, 32), blk, 0, stream>>>(xb, Wv, bv, Vf);
        l2norm_f64bf16<<<dim3(P), blk, 0, stream>>>(Qd, Qh);
        l2norm_f64bf16<<<dim3(P), blk, 0, stream>>>(Kd, Kh);
        gemm_score<<<dim3(32, 32), blk, 0, stream>>>(Qh, Kh, Sf);
        topk_route<<<dim3(P), blk, 0, stream>>>(Sf, Qd, Kd, Vf, routes, weights, feat, b);
    }
}